// Round 1
// baseline (558.725 us; speedup 1.0000x reference)
//
#include <hip/hip_runtime.h>
#include <stdint.h>

#define DEV __device__ __forceinline__

typedef __attribute__((ext_vector_type(8))) short short8;    // 8 bf16 = 4 VGPRs (MFMA A/B frag)
typedef __attribute__((ext_vector_type(4))) short short4v;   // 4 bf16 = 8B
typedef __attribute__((ext_vector_type(4))) float floatx4;   // MFMA C/D frag

constexpr int TM = 64;          // rows per block (4 waves x 16 rows)
constexpr int NB = 131072;      // batch

// ---- packed bf16 weight layout in d_ws (ushort element offsets) ----
// big layers (N=256) are split into two N-halves of 128; chunk = [128|64|32 n][32 k] bf16
constexpr int OFF_W1 = 0;               constexpr int NE_W1 = 2*7*4096;   // K=224(pad from 200), N=256
constexpr int OFF_W2 = OFF_W1+NE_W1;    constexpr int NE_W2 = 2*8*4096;   // K=256, N=256
constexpr int OFF_W3 = OFF_W2+NE_W2;    constexpr int NE_W3 = 8*4096;     // K=256, N=128
constexpr int OFF_WV1= OFF_W3+NE_W3;    constexpr int NE_WV1= 4*2048;     // K=128, N=64
constexpr int OFF_WA1= OFF_WV1+NE_WV1;  constexpr int NE_WA1= 3*4*2048;   // 3 x (K=128,N=64)
constexpr int OFF_WA2= OFF_WA1+NE_WA1;  constexpr int NE_WA2= 3*2*1024;   // 3 x (K=64, N=32)
constexpr int NWQ = OFF_WA2+NE_WA2;     // 194560 elems
static_assert(NWQ == 194560, "wq size");

// ---- const (bias/gain/etc) float offsets in d_ws after weights ----
constexpr int C_B1=0, C_G1=256, C_BE1=512, C_B2=768, C_G2=1024, C_BE2=1280,
  C_B3=1536, C_G3=1664, C_BE3=1792, C_BV1=1920, C_GV=1984, C_BEV=2048,
  C_WV2=2112, C_BV2=2176, C_BA1=2177, C_GA=2369, C_BEA=2561, C_BA2=2753;
constexpr int NCONST=2849;

struct Ptrs {
  const float *state,*td,*W1,*b1,*g1,*be1,*W2,*b2,*g2,*be2,*W3,*b3,*g3,*be3,
    *Wv1,*bv1,*gv,*bev,*Wv2,*bv2,*Wa1,*ba1,*ga,*bea,*Wa2,*ba2;
  const int *et;
};

// float -> bf16 round-to-nearest-even (bit trick; inputs are finite)
DEV unsigned short f2bf(float x){
  uint32_t u = __float_as_uint(x);
  u += 0x7fffu + ((u>>16)&1u);
  return (unsigned short)(u>>16);
}

// =====================================================================
// prep kernel: quantize+transpose+chunk all weights into d_ws, copy consts.
// Packed layout per layer: [nh][kc][n(128)][kin(32)] (or fewer n for small N).
// The k-index is PERMUTED to match the producing layer's activation layout:
//   N=256 producer: act position p holds col c with p = 16*(c&15) + (c>>4)
//   N=128 producer: p = 8*(c&15) + (c>>4)
//   N=64  producer: p = 4*(c&15) + (c>>4)
// so for weight position k we fetch source col c = inverse(k).
// =====================================================================
__global__ void prep_kernel(Ptrs p, unsigned short* __restrict__ wq, float* __restrict__ cq){
  int idx = blockIdx.x*256 + threadIdx.x;
  if (idx < NWQ) {
    float v = 0.f;
    if (idx < OFF_W2) {                       // W1: input x unpermuted, K pad 200->224
      int l = idx;
      int nh = l / 28672, l2 = l % 28672;
      int kc = l2 / 4096, n = nh*128 + ((l2>>5)&127), kin = l2&31;
      int k = kc*32 + kin;
      if (k < 200) v = p.W1[k*256 + n];
    } else if (idx < OFF_W3) {                // W2: input h1 (perm16)
      int l = idx - OFF_W2;
      int nh = l / 32768, l2 = l % 32768;
      int kc = l2 / 4096, n = nh*128 + ((l2>>5)&127), kin = l2&31;
      int k = kc*32 + kin;
      int c = 16*(k&15) + (k>>4);
      v = p.W2[c*256 + n];
    } else if (idx < OFF_WV1) {               // W3: input h2 (perm16)
      int l = idx - OFF_W3;
      int kc = l / 4096, n = (l>>5)&127, kin = l&31;
      int k = kc*32 + kin;
      int c = 16*(k&15) + (k>>4);
      v = p.W3[c*128 + n];
    } else if (idx < OFF_WA1) {               // Wv1: input f (perm128)
      int l = idx - OFF_WV1;
      int kc = l / 2048, n = (l>>5)&63, kin = l&31;
      int k = kc*32 + kin;
      int c = 16*(k&7) + (k>>3);
      v = p.Wv1[c*64 + n];
    } else if (idx < OFF_WA2) {               // Wa1[e]: input f (perm128)
      int l = idx - OFF_WA1;
      int e = l / 8192, l2 = l & 8191;
      int kc = l2 / 2048, n = (l2>>5)&63, kin = l2&31;
      int k = kc*32 + kin;
      int c = 16*(k&7) + (k>>3);
      v = p.Wa1[e*8192 + c*64 + n];
    } else {                                  // Wa2[e]: input ha (perm64)
      int l = idx - OFF_WA2;
      int e = l / 2048, l2 = l & 2047;
      int kc = l2 / 1024, n = (l2>>5)&31, kin = l2&31;
      int k = kc*32 + kin;
      int c = 16*(k&3) + (k>>2);
      v = p.Wa2[e*2048 + c*32 + n];
    }
    wq[idx] = f2bf(v);
  } else if (idx < NWQ + NCONST) {
    int ci = idx - NWQ;
    const float* src; int off;
    if      (ci < 256)  { src=p.b1;  off=ci; }
    else if (ci < 512)  { src=p.g1;  off=ci-256; }
    else if (ci < 768)  { src=p.be1; off=ci-512; }
    else if (ci < 1024) { src=p.b2;  off=ci-768; }
    else if (ci < 1280) { src=p.g2;  off=ci-1024; }
    else if (ci < 1536) { src=p.be2; off=ci-1280; }
    else if (ci < 1664) { src=p.b3;  off=ci-1536; }
    else if (ci < 1792) { src=p.g3;  off=ci-1664; }
    else if (ci < 1920) { src=p.be3; off=ci-1792; }
    else if (ci < 1984) { src=p.bv1; off=ci-1920; }
    else if (ci < 2048) { src=p.gv;  off=ci-1984; }
    else if (ci < 2112) { src=p.bev; off=ci-2048; }
    else if (ci < 2176) { src=p.Wv2; off=ci-2112; }
    else if (ci < 2177) { src=p.bv2; off=ci-2176; }
    else if (ci < 2369) { src=p.ba1; off=ci-2177; }
    else if (ci < 2561) { src=p.ga;  off=ci-2369; }
    else if (ci < 2753) { src=p.bea; off=ci-2561; }
    else                { src=p.ba2; off=ci-2753; }
    cq[ci] = src[off];
  }
}

// =====================================================================
// main kernel helpers
// =====================================================================
template<int N> DEV void zacc(floatx4 (&acc)[16]){
  const floatx4 z = {0.f,0.f,0.f,0.f};
  #pragma unroll
  for (int t=0;t<N;t++) acc[t]=z;
}

// K-loop: acc[TB..TB+NT) += A(16 x 32k) * B(32k x NT*16), NK k-chunks.
// Weight chunks double-buffered in LDS; staged global->VGPR->LDS with
// one-chunk prefetch (loads for kc+1 issued right after the barrier).
// Buffer for chunk kc is (pb+kc)&1; invariant: writing chunk kc's buffer
// only clobbers chunk kc-2, and the barrier chain guarantees all waves
// are past compute(kc-2) by then (holds across layers too).
template<int NT,int NK,int TB>
DEV void mfma_loop(floatx4 (&acc)[16], const unsigned short* __restrict__ wsrc,
                   const unsigned short* ap,      // per-lane A base: act + (rowWave+ln)*264 + aBase + q*8
                   unsigned short* wl,            // wbufs base
                   const unsigned short* wrd,     // per-lane B base: wbufs + ln*32 + q*8
                   int wid, int lane, int& pb)
{
  constexpr int CE = NT*16*32;        // chunk elems (bf16)
  constexpr int NI = (CE*2)/1024;     // 1KB (16B/lane) stores per chunk
  constexpr int NIW = (NI+3)/4;       // per-wave share
  uint4 sv[NIW];
  #pragma unroll
  for (int ii=0;ii<NIW;ii++){ int i=wid+ii*4; if (i<NI) sv[ii] = *(const uint4*)(wsrc + i*512 + lane*8); }
  #pragma unroll
  for (int kc=0;kc<NK;kc++){
    const int cbuf = (pb+kc)&1;
    #pragma unroll
    for (int ii=0;ii<NIW;ii++){ int i=wid+ii*4; if (i<NI) *(uint4*)(wl + cbuf*4096 + i*512 + lane*8) = sv[ii]; }
    __syncthreads();
    if (kc+1<NK){
      #pragma unroll
      for (int ii=0;ii<NIW;ii++){ int i=wid+ii*4; if (i<NI) sv[ii] = *(const uint4*)(wsrc + (kc+1)*CE + i*512 + lane*8); }
    }
    short8 a = *(const short8*)(ap + kc*32);
    #pragma unroll
    for (int t=0;t<NT;t++){
      short8 b = *(const short8*)(wrd + cbuf*4096 + t*512);
      acc[TB+t] = __builtin_amdgcn_mfma_f32_16x16x32_bf16(a, b, acc[TB+t], 0, 0, 0);
    }
  }
  pb = (pb+NK)&1;
}

// bias + LayerNorm + ReLU, fully in registers. C-layout: col=ln+16t, row=q*4+r.
// Row stats via in-lane sum over t then shfl_xor over the 16 lanes of the quad.
template<int NT>
DEV void bias_ln_relu(floatx4 (&acc)[16], const float* cb, int bo, int go, int beo, int lane){
  const int ln = lane&15;
  constexpr float invN = 1.0f/(16*NT);
  float s[4]={0,0,0,0}, ss[4]={0,0,0,0};
  #pragma unroll
  for (int t=0;t<NT;t++){
    float bb = cb[bo + ln + 16*t];
    #pragma unroll
    for (int r=0;r<4;r++){
      float v = acc[t][r] + bb;
      acc[t][r] = v; s[r]+=v; ss[r]+=v*v;
    }
  }
  float mu[4], rs[4];
  #pragma unroll
  for (int r=0;r<4;r++){
    #pragma unroll
    for (int d=1;d<16;d<<=1){ s[r]+=__shfl_xor(s[r],d,64); ss[r]+=__shfl_xor(ss[r],d,64); }
    mu[r]=s[r]*invN;
    float var = ss[r]*invN - mu[r]*mu[r];
    rs[r] = rsqrtf(var + 1e-5f);
  }
  #pragma unroll
  for (int t=0;t<NT;t++){
    float gg = cb[go + ln + 16*t], bb = cb[beo + ln + 16*t];
    #pragma unroll
    for (int r=0;r<4;r++){
      float y = (acc[t][r]-mu[r])*rs[r]*gg + bb;
      acc[t][r] = fmaxf(y, 0.0f);
    }
  }
}

// write activations to LDS bf16 in the PERMUTED layout: position p=ln*NT+t
// (so each row's in-lane t-run is contiguous -> vector ds_write; the
// consuming layer's weights were k-permuted to match in prep_kernel).
template<int NT>
DEV void store_act_perm(const floatx4 (&acc)[16], unsigned short* actRowBase, int dstElemBase, int lane){
  const int q=lane>>4, ln=lane&15;
  #pragma unroll
  for (int r=0;r<4;r++){
    int row = q*4+r;
    unsigned short* pp = actRowBase + row*264 + dstElemBase + ln*NT;
    if constexpr (NT==16){
      short8 v0, v1;
      #pragma unroll
      for (int j=0;j<8;j++){ v0[j]=(short)f2bf(acc[j][r]); v1[j]=(short)f2bf(acc[8+j][r]); }
      *(short8*)pp = v0;
      *(short8*)(pp+8) = v1;
    } else if constexpr (NT==8){
      short8 v;
      #pragma unroll
      for (int j=0;j<8;j++) v[j]=(short)f2bf(acc[j][r]);
      *(short8*)pp = v;
    } else {
      short4v v;
      #pragma unroll
      for (int j=0;j<NT;j++) v[j]=(short)f2bf(acc[j][r]);
      *(short4v*)pp = v;
    }
  }
}

// =====================================================================
// fused forward: 64 rows/block, 4 waves x 16 rows, everything in one kernel.
// LDS: act[64][264] bf16 (stride 264 = 256+8 pad -> balanced banks),
//      2 x 8KB weight chunk buffers, 2849 floats of consts. Total 61.5 KB.
// =====================================================================
__global__ __launch_bounds__(256,2) void dqn_main(
    const float* __restrict__ state, const float* __restrict__ td,
    const int* __restrict__ et, const unsigned short* __restrict__ wq,
    const float* __restrict__ cq, float* __restrict__ out)
{
  __shared__ __align__(16) unsigned short act[TM*264];
  __shared__ __align__(16) unsigned short wbufs[2*4096];
  __shared__ float cb[NCONST];

  const int tid=threadIdx.x, wid=tid>>6, lane=tid&63, q=lane>>4, ln=lane&15;
  const int rowBlk = blockIdx.x*TM, rowWave = wid*16;

  // stage consts
  for (int i=tid;i<NCONST;i+=256) cb[i]=cq[i];
  // stage x = [state | td | zeros] as bf16, cols 0..223
  for (int i=tid;i<TM*224;i+=256){
    int r = i/224, c = i - r*224;
    float v = 0.f;
    if (c < 199) v = state[(size_t)(rowBlk+r)*199 + c];
    else if (c == 199) v = td[rowBlk+r];
    act[r*264 + c] = f2bf(v);
  }
  int etv[4];
  #pragma unroll
  for (int r=0;r<4;r++) etv[r] = et[rowBlk + rowWave + q*4 + r];

  floatx4 acc[16];
  int pb = 0;
  const unsigned short* apL   = act + (rowWave+ln)*264 + q*8;        // A frags, input cols at 0
  const unsigned short* ap192 = apL + 192;                           // A frags for ha (cols 192..)
  const unsigned short* wrd   = wbufs + ln*32 + q*8;                 // B frag lane base
  unsigned short* actW = act + rowWave*264;

  // L1: x(224) -> h1(256)   [first barrier also covers x/const staging]
  zacc<16>(acc);
  mfma_loop<8,7,0>(acc, wq+OFF_W1,          apL, wbufs, wrd, wid, lane, pb);
  mfma_loop<8,7,8>(acc, wq+OFF_W1+7*4096,   apL, wbufs, wrd, wid, lane, pb);
  bias_ln_relu<16>(acc, cb, C_B1, C_G1, C_BE1, lane);
  store_act_perm<16>(acc, actW, 0, lane);

  // L2: h1(256) -> h2(256)
  zacc<16>(acc);
  mfma_loop<8,8,0>(acc, wq+OFF_W2,          apL, wbufs, wrd, wid, lane, pb);
  mfma_loop<8,8,8>(acc, wq+OFF_W2+8*4096,   apL, wbufs, wrd, wid, lane, pb);
  bias_ln_relu<16>(acc, cb, C_B2, C_G2, C_BE2, lane);
  store_act_perm<16>(acc, actW, 0, lane);

  // L3: h2(256) -> f(128)
  zacc<8>(acc);
  mfma_loop<8,8,0>(acc, wq+OFF_W3, apL, wbufs, wrd, wid, lane, pb);
  bias_ln_relu<8>(acc, cb, C_B3, C_G3, C_BE3, lane);
  store_act_perm<8>(acc, actW, 0, lane);

  // value head: f(128) -> v1(64) -> v (v1 stays in registers)
  zacc<4>(acc);
  mfma_loop<4,4,0>(acc, wq+OFF_WV1, apL, wbufs, wrd, wid, lane, pb);
  bias_ln_relu<4>(acc, cb, C_BV1, C_GV, C_BEV, lane);
  float vrow[4];
  {
    float wv[4];
    #pragma unroll
    for (int t=0;t<4;t++) wv[t] = cb[C_WV2 + ln + 16*t];
    #pragma unroll
    for (int r=0;r<4;r++){
      float s = 0.f;
      #pragma unroll
      for (int t=0;t<4;t++) s += acc[t][r]*wv[t];
      #pragma unroll
      for (int d=1;d<16;d<<=1) s += __shfl_xor(s,d,64);
      vrow[r] = s + cb[C_BV2];
    }
  }

  // advantage heads: compute all 3, select by event_type
  float advsel[2][4] = {};
  for (int e=0;e<3;e++){
    zacc<4>(acc);
    mfma_loop<4,4,0>(acc, wq+OFF_WA1+e*8192, apL, wbufs, wrd, wid, lane, pb);
    bias_ln_relu<4>(acc, cb, C_BA1+e*64, C_GA+e*64, C_BEA+e*64, lane);
    store_act_perm<4>(acc, actW, 192, lane);        // ha -> cols 192..255
    zacc<2>(acc);
    mfma_loop<2,2,0>(acc, wq+OFF_WA2+e*2048, ap192, wbufs, wrd, wid, lane, pb);
    #pragma unroll
    for (int t=0;t<2;t++){
      float b2v = cb[C_BA2 + e*32 + ln + 16*t];
      #pragma unroll
      for (int r=0;r<4;r++){
        float a = acc[t][r] + b2v;
        if (etv[r]==e) advsel[t][r] = a;
      }
    }
  }

  // out = v + adv - mean(adv)
  #pragma unroll
  for (int r=0;r<4;r++){
    float sm = advsel[0][r] + advsel[1][r];
    #pragma unroll
    for (int d=1;d<16;d<<=1) sm += __shfl_xor(sm,d,64);
    float mean = sm * (1.0f/32.0f);
    int R = rowBlk + rowWave + q*4 + r;
    #pragma unroll
    for (int t=0;t<2;t++)
      out[(size_t)R*32 + ln + 16*t] = vrow[r] + advsel[t][r] - mean;
  }
}

// =====================================================================
extern "C" void kernel_launch(void* const* d_in, const int* in_sizes, int n_in,
                              void* d_out, int out_size, void* d_ws, size_t ws_size,
                              hipStream_t stream)
{
  Ptrs p;
  p.state=(const float*)d_in[0];  p.td =(const float*)d_in[1];
  p.W1 =(const float*)d_in[2];  p.b1 =(const float*)d_in[3];  p.g1 =(const float*)d_in[4];  p.be1=(const float*)d_in[5];
  p.W2 =(const float*)d_in[6];  p.b2 =(const float*)d_in[7];  p.g2 =(const float*)d_in[8];  p.be2=(const float*)d_in[9];
  p.W3 =(const float*)d_in[10]; p.b3 =(const float*)d_in[11]; p.g3 =(const float*)d_in[12]; p.be3=(const float*)d_in[13];
  p.Wv1=(const float*)d_in[14]; p.bv1=(const float*)d_in[15]; p.gv =(const float*)d_in[16]; p.bev=(const float*)d_in[17];
  p.Wv2=(const float*)d_in[18]; p.bv2=(const float*)d_in[19];
  p.Wa1=(const float*)d_in[20]; p.ba1=(const float*)d_in[21]; p.ga =(const float*)d_in[22]; p.bea=(const float*)d_in[23];
  p.Wa2=(const float*)d_in[24]; p.ba2=(const float*)d_in[25];
  p.et =(const int*)d_in[26];

  unsigned short* wq = (unsigned short*)d_ws;
  float* cq = (float*)((char*)d_ws + (size_t)NWQ*2);   // 389120 B of weights, then 11396 B consts

  const int prepN = NWQ + NCONST;
  hipLaunchKernelGGL(prep_kernel, dim3((prepN+255)/256), dim3(256), 0, stream, p, wq, cq);
  hipLaunchKernelGGL(dqn_main, dim3(NB/TM), dim3(256), 0, stream,
                     p.state, p.td, p.et, (const unsigned short*)wq, (const float*)cq, (float*)d_out);
}

// Round 2
// 341.468 us; speedup vs baseline: 1.6362x; 1.6362x over previous
//
#include <hip/hip_runtime.h>
#include <stdint.h>

#define DEV __device__ __forceinline__

typedef __attribute__((ext_vector_type(8))) short short8;    // 8 bf16 (MFMA A/B frag)
typedef __attribute__((ext_vector_type(4))) short short4v;   // 4 bf16
typedef __attribute__((ext_vector_type(4))) float floatx4;   // MFMA C/D frag

constexpr int TM  = 64;     // rows per block
constexpr int NB  = 131072; // batch
constexpr int AST = 264;    // act row stride (bf16 elems), 264 = 33*8 keeps b128 align

// ---- packed bf16 weight layout in d_ws (element offsets) ----
// per layer: [w][kc][ct][lane(64)][8] ; lane l: n = wSW + ct*16 + (l&15),
//                                       k = kc*32 + (l>>4)*8 + j
constexpr int OFF_W1 = 0;        // 4w x 7kc x 4ct x 512   (K=224 pad of 200, N=256)
constexpr int OFF_W2 = 57344;    // 4w x 8 x 4 x 512       (K=256, N=256)
constexpr int OFF_W3 = 122880;   // 4w x 8 x 2 x 512       (K=256, N=128, SW=32)
constexpr int OFF_WH = 155648;   // 4h x 4 x 4 x 512       (K=128, N=64; h=0..2 adv, h=3 value)
constexpr int OFF_WA2= 188416;   // 3h x 2 x 2 x 512       (K=64,  N=32)
constexpr int NWQ    = 194560;

// ---- const (bias/gain/etc) float offsets after weights ----
constexpr int C_B1=0, C_G1=256, C_BE1=512, C_B2=768, C_G2=1024, C_BE2=1280,
  C_B3=1536, C_G3=1664, C_BE3=1792, C_BV1=1920, C_GV=1984, C_BEV=2048,
  C_WV2=2112, C_BV2=2176, C_BA1=2177, C_GA=2369, C_BEA=2561, C_BA2=2753;
constexpr int NCONST=2849;

struct Ptrs {
  const float *state,*td,*W1,*b1,*g1,*be1,*W2,*b2,*g2,*be2,*W3,*b3,*g3,*be3,
    *Wv1,*bv1,*gv,*bev,*Wv2,*bv2,*Wa1,*ba1,*ga,*bea,*Wa2,*ba2;
  const int *et;
};

DEV unsigned short f2bf(float x){
  uint32_t u = __float_as_uint(x);
  u += 0x7fffu + ((u>>16)&1u);
  return (unsigned short)(u>>16);
}

// =====================================================================
// prep: quantize + transpose + pack weights; copy consts.
// k-permutations invert the producer's in-lane packed activation layout:
//   SW=64 producer (L1,L2): pos p = 4*(c&15) + ((c>>4)&3)   within 64-block
//   SW=32 producer (L3):    pos p = 2*(c&15) + ((c>>4)&1)   within 32-block
//   head producer (64cols): pos p = 4*(c&15) + (c>>4)
// =====================================================================
__global__ void prep_kernel(Ptrs p, unsigned short* __restrict__ wq, float* __restrict__ cq){
  int idx = blockIdx.x*256 + threadIdx.x;
  if (idx < NWQ) {
    float v = 0.f;
    if (idx < OFF_W2) {                       // W1: k unpermuted (x staged naturally)
      int e = idx, w = e/14336, r = e%14336;
      int kc = r>>11, ct=(r>>9)&3, l=(r>>3)&63, j=r&7;
      int n = w*64 + ct*16 + (l&15);
      int k = kc*32 + (l>>4)*8 + j;
      if (k < 200) v = p.W1[k*256 + n];
    } else if (idx < OFF_W3) {                // W2: producer SW=64
      int e = idx-OFF_W2, w=e>>14, r=e&16383;
      int kc=r>>11, ct=(r>>9)&3, l=(r>>3)&63, j=r&7;
      int n = w*64 + ct*16 + (l&15);
      int k = kc*32 + (l>>4)*8 + j;
      int c = (k & ~63) + 16*(k&3) + ((k&63)>>2);
      v = p.W2[c*256 + n];
    } else if (idx < OFF_WH) {                // W3: producer SW=64, this layer SW=32
      int e = idx-OFF_W3, w=e>>13, r=e&8191;
      int kc=r>>10, ct=(r>>9)&1, l=(r>>3)&63, j=r&7;
      int n = w*32 + ct*16 + (l&15);
      int k = kc*32 + (l>>4)*8 + j;
      int c = (k & ~63) + 16*(k&3) + ((k&63)>>2);
      v = p.W3[c*128 + n];
    } else if (idx < OFF_WA2) {               // Wv1/Wa1: producer SW=32 (f)
      int e = idx-OFF_WH, h=e>>13, r=e&8191;
      int kc=r>>11, ct=(r>>9)&3, l=(r>>3)&63, j=r&7;
      int n = ct*16 + (l&15);
      int k = kc*32 + (l>>4)*8 + j;
      int c = (k & ~31) + 16*(k&1) + ((k&31)>>1);
      v = (h<3) ? p.Wa1[h*8192 + c*64 + n] : p.Wv1[c*64 + n];
    } else {                                  // Wa2: producer = head wave (64 cols)
      int e = idx-OFF_WA2, h=e>>11, r=e&2047;
      int kc=r>>10, ct=(r>>9)&1, l=(r>>3)&63, j=r&7;
      int n = ct*16 + (l&15);
      int k = kc*32 + (l>>4)*8 + j;       // k in 0..63
      int c = 16*(k&3) + (k>>2);
      v = p.Wa2[h*2048 + c*32 + n];
    }
    wq[idx] = f2bf(v);
  } else if (idx < NWQ + NCONST) {
    int ci = idx - NWQ;
    const float* src; int off;
    if      (ci < 256)  { src=p.b1;  off=ci; }
    else if (ci < 512)  { src=p.g1;  off=ci-256; }
    else if (ci < 768)  { src=p.be1; off=ci-512; }
    else if (ci < 1024) { src=p.b2;  off=ci-768; }
    else if (ci < 1280) { src=p.g2;  off=ci-1024; }
    else if (ci < 1536) { src=p.be2; off=ci-1280; }
    else if (ci < 1664) { src=p.b3;  off=ci-1536; }
    else if (ci < 1792) { src=p.g3;  off=ci-1664; }
    else if (ci < 1920) { src=p.be3; off=ci-1792; }
    else if (ci < 1984) { src=p.bv1; off=ci-1920; }
    else if (ci < 2048) { src=p.gv;  off=ci-1984; }
    else if (ci < 2112) { src=p.bev; off=ci-2048; }
    else if (ci < 2176) { src=p.Wv2; off=ci-2112; }
    else if (ci < 2177) { src=p.bv2; off=ci-2176; }
    else if (ci < 2369) { src=p.ba1; off=ci-2177; }
    else if (ci < 2561) { src=p.ga;  off=ci-2369; }
    else if (ci < 2753) { src=p.bea; off=ci-2561; }
    else                { src=p.ba2; off=ci-2753; }
    cq[ci] = src[off];
  }
}

// =====================================================================
// device helpers
// =====================================================================
template<int N>
DEV void loadB(short8 (&B)[N], const unsigned short* __restrict__ src, int lane){
  #pragma unroll
  for (int i=0;i<N;i++) B[i] = *(const short8*)(src + i*512 + lane*8);
}

template<int RT,int CT>
DEV void zeroAcc(floatx4 (&acc)[RT][CT]){
  const floatx4 z = {0.f,0.f,0.f,0.f};
  #pragma unroll
  for (int rt=0;rt<RT;rt++)
    #pragma unroll
    for (int ct=0;ct<CT;ct++) acc[rt][ct]=z;
}

// kc-outer so the 4*CT MFMAs per kc are independent (16 chains of depth KC)
template<int KC,int CT>
DEV void runGemm(floatx4 (&acc)[4][CT], const short8 (&B)[KC*CT],
                 const unsigned short* aBase, int aOff){
  #pragma unroll
  for (int kc=0;kc<KC;kc++){
    short8 a[4];
    #pragma unroll
    for (int rt=0;rt<4;rt++)
      a[rt] = *(const short8*)(aBase + rt*16*AST + aOff + kc*32);
    #pragma unroll
    for (int rt=0;rt<4;rt++)
      #pragma unroll
      for (int ct=0;ct<CT;ct++)
        acc[rt][ct] = __builtin_amdgcn_mfma_f32_16x16x32_bf16(a[rt], B[kc*CT+ct], acc[rt][ct], 0,0,0);
  }
}

// bias add + per-row partial (s,ss) over this wave's cols -> pstat[w]
template<int CT>
DEV void biasStatsWrite(floatx4 (&acc)[4][CT], const float* __restrict__ cq, int bo, int colBase,
                        float2* pstatw, int ln, int q){
  float bias[CT];
  #pragma unroll
  for (int ct=0;ct<CT;ct++) bias[ct]=cq[bo+colBase+ct*16+ln];
  #pragma unroll
  for (int rt=0;rt<4;rt++){
    float s[4]={0,0,0,0}, ss[4]={0,0,0,0};
    #pragma unroll
    for (int ct=0;ct<CT;ct++){
      #pragma unroll
      for (int r=0;r<4;r++){
        float v=acc[rt][ct][r]+bias[ct];
        acc[rt][ct][r]=v; s[r]+=v; ss[r]+=v*v;
      }
    }
    #pragma unroll
    for (int r=0;r<4;r++){
      #pragma unroll
      for (int d=1;d<16;d<<=1){ s[r]+=__shfl_xor(s[r],d); ss[r]+=__shfl_xor(ss[r],d); }
      if (ln==0) pstatw[rt*16+q*4+r] = make_float2(s[r], ss[r]);
    }
  }
}

// LN apply + relu + packed bf16 act write at position colBase + ln*CT + ct
template<int CT>
DEV void lnWrite(floatx4 (&acc)[4][CT], const float* __restrict__ cq, int go, int beo, int colBase,
                 const float2* fstat, unsigned short* act_, int ln, int q){
  float g[CT], be[CT];
  #pragma unroll
  for (int ct=0;ct<CT;ct++){ g[ct]=cq[go+colBase+ct*16+ln]; be[ct]=cq[beo+colBase+ct*16+ln]; }
  #pragma unroll
  for (int rt=0;rt<4;rt++){
    #pragma unroll
    for (int r=0;r<4;r++){
      int row=rt*16+q*4+r;
      float2 st=fstat[row];
      unsigned short* pp = act_ + row*AST + colBase + ln*CT;
      if constexpr (CT==4){
        short4v vv;
        #pragma unroll
        for (int ct=0;ct<CT;ct++){
          float y=(acc[rt][ct][r]-st.x)*st.y*g[ct]+be[ct];
          vv[ct]=(short)f2bf(fmaxf(y,0.f));
        }
        *(short4v*)pp = vv;
      } else {
        uint32_t pk=0;
        #pragma unroll
        for (int ct=0;ct<CT;ct++){
          float y=(acc[rt][ct][r]-st.x)*st.y*g[ct]+be[ct];
          pk |= ((uint32_t)f2bf(fmaxf(y,0.f)))<<(16*ct);
        }
        *(uint32_t*)pp = pk;
      }
    }
  }
}

// =====================================================================
// fused forward: 64 rows/block, 4 waves split COLUMNS; B in registers.
// =====================================================================
__global__ __launch_bounds__(256,2) void dqn_main(
    const float* __restrict__ state, const float* __restrict__ td,
    const int* __restrict__ et, const unsigned short* __restrict__ wq,
    const float* __restrict__ cq, float* __restrict__ out)
{
  __shared__ __align__(16) unsigned short act[TM*AST];   // 33.8 KB
  __shared__ float2 pstat[4*64];                          // 2 KB
  __shared__ float2 fstat[64];                            // 0.5 KB
  __shared__ float  advbuf[64*32];                        // 8 KB
  __shared__ float  vbuf[64];
  __shared__ int    etl[64];

  const int tid=threadIdx.x, w=tid>>6, lane=tid&63, q=lane>>4, ln=lane&15;
  const int rowBlk = blockIdx.x*TM;

  // ---- stage x = [state | td | 0pad] bf16 at natural positions 0..223 ----
  {
    int r = tid>>2, q4 = tid&3, c0 = q4*56;
    const float* srow = state + (size_t)(rowBlk+r)*199;
    float tdv = td[rowBlk+r];
    unsigned short* arow = act + r*AST;
    #pragma unroll
    for (int cc=0; cc<28; cc++){
      int c = c0 + cc*2;
      float v0 = (c  <199)? srow[c]   : (c  ==199? tdv : 0.f);
      float v1 = (c+1<199)? srow[c+1] : (c+1==199? tdv : 0.f);
      uint32_t pk = (uint32_t)f2bf(v0) | ((uint32_t)f2bf(v1)<<16);
      *(uint32_t*)(arow + c) = pk;
    }
    if (tid < 64) etl[tid] = et[rowBlk+tid];
  }
  __syncthreads();

  const unsigned short* aBase = act + ln*AST + q*8;
  floatx4 acc[4][4];

  // ---- L1: x(224) -> h1(256), wave cols [64w,64w+64) ----
  {
    short8 B[28];
    loadB<28>(B, wq + OFF_W1 + w*14336, lane);
    zeroAcc<4,4>(acc);
    runGemm<7,4>(acc, B, aBase, 0);
  }
  biasStatsWrite<4>(acc, cq, C_B1, w*64, &pstat[w*64], ln, q);
  __syncthreads();
  if (tid<64){
    float s=0, ss=0;
    #pragma unroll
    for (int ww=0;ww<4;ww++){ float2 pp=pstat[ww*64+tid]; s+=pp.x; ss+=pp.y; }
    float mu=s*(1.f/256.f), var=ss*(1.f/256.f)-mu*mu;
    fstat[tid]=make_float2(mu, rsqrtf(var+1e-5f));
  }
  __syncthreads();
  lnWrite<4>(acc, cq, C_G1, C_BE1, w*64, fstat, act, ln, q);
  __syncthreads();

  // ---- L2: h1(256) -> h2(256) ----
  {
    short8 B[32];
    loadB<32>(B, wq + OFF_W2 + w*16384, lane);
    zeroAcc<4,4>(acc);
    runGemm<8,4>(acc, B, aBase, 0);
  }
  biasStatsWrite<4>(acc, cq, C_B2, w*64, &pstat[w*64], ln, q);
  __syncthreads();
  if (tid<64){
    float s=0, ss=0;
    #pragma unroll
    for (int ww=0;ww<4;ww++){ float2 pp=pstat[ww*64+tid]; s+=pp.x; ss+=pp.y; }
    float mu=s*(1.f/256.f), var=ss*(1.f/256.f)-mu*mu;
    fstat[tid]=make_float2(mu, rsqrtf(var+1e-5f));
  }
  __syncthreads();
  lnWrite<4>(acc, cq, C_G2, C_BE2, w*64, fstat, act, ln, q);
  __syncthreads();

  // ---- L3: h2(256) -> f(128), wave cols [32w,32w+32) ----
  {
    floatx4 acc2[4][2];
    {
      short8 B[16];
      loadB<16>(B, wq + OFF_W3 + w*8192, lane);
      zeroAcc<4,2>(acc2);
      runGemm<8,2>(acc2, B, aBase, 0);
    }
    biasStatsWrite<2>(acc2, cq, C_B3, w*32, &pstat[w*64], ln, q);
    __syncthreads();
    if (tid<64){
      float s=0, ss=0;
      #pragma unroll
      for (int ww=0;ww<4;ww++){ float2 pp=pstat[ww*64+tid]; s+=pp.x; ss+=pp.y; }
      float mu=s*(1.f/128.f), var=ss*(1.f/128.f)-mu*mu;
      fstat[tid]=make_float2(mu, rsqrtf(var+1e-5f));
    }
    __syncthreads();
    lnWrite<2>(acc2, cq, C_G3, C_BE3, w*32, fstat, act, ln, q);
    __syncthreads();
  }

  // ---- heads: wave w = head w (0..2 adv, 3 value). f(128) -> 64, LN in-wave ----
  {
    short8 B[16];
    loadB<16>(B, wq + OFF_WH + w*8192, lane);
    zeroAcc<4,4>(acc);
    runGemm<4,4>(acc, B, aBase, 0);
  }
  {
    const int bo = (w<3)? C_BA1+w*64 : C_BV1;
    const int go = (w<3)? C_GA +w*64 : C_GV;
    const int beo= (w<3)? C_BEA+w*64 : C_BEV;
    float bias[4], g[4], be[4];
    #pragma unroll
    for (int ct=0;ct<4;ct++){ bias[ct]=cq[bo+ct*16+ln]; g[ct]=cq[go+ct*16+ln]; be[ct]=cq[beo+ct*16+ln]; }
    #pragma unroll
    for (int rt=0;rt<4;rt++){
      float s[4]={0,0,0,0}, ss[4]={0,0,0,0};
      #pragma unroll
      for (int ct=0;ct<4;ct++)
        #pragma unroll
        for (int r=0;r<4;r++){
          float v=acc[rt][ct][r]+bias[ct];
          acc[rt][ct][r]=v; s[r]+=v; ss[r]+=v*v;
        }
      float mu[4], rs[4];
      #pragma unroll
      for (int r=0;r<4;r++){
        #pragma unroll
        for (int d=1;d<16;d<<=1){ s[r]+=__shfl_xor(s[r],d); ss[r]+=__shfl_xor(ss[r],d); }
        mu[r]=s[r]*(1.f/64.f);
        rs[r]=rsqrtf(ss[r]*(1.f/64.f)-mu[r]*mu[r]+1e-5f);
      }
      #pragma unroll
      for (int ct=0;ct<4;ct++)
        #pragma unroll
        for (int r=0;r<4;r++)
          acc[rt][ct][r]=fmaxf((acc[rt][ct][r]-mu[r])*rs[r]*g[ct]+be[ct], 0.f);
    }
  }

  // value head: v = v1 . Wv2 + bv2 (in regs)
  if (w==3){
    float wv[4];
    #pragma unroll
    for (int ct=0;ct<4;ct++) wv[ct]=cq[C_WV2+ct*16+ln];
    float bv2v = cq[C_BV2];
    #pragma unroll
    for (int rt=0;rt<4;rt++){
      float dd[4]={0,0,0,0};
      #pragma unroll
      for (int ct=0;ct<4;ct++)
        #pragma unroll
        for (int r=0;r<4;r++) dd[r]+=acc[rt][ct][r]*wv[ct];
      #pragma unroll
      for (int r=0;r<4;r++){
        #pragma unroll
        for (int d=1;d<16;d<<=1) dd[r]+=__shfl_xor(dd[r],d);
        if (ln==0) vbuf[rt*16+q*4+r]=dd[r]+bv2v;
      }
    }
  }
  __syncthreads();   // all f-reads complete before ha overwrites act

  // adv heads: write ha into act cols [64w,64w+64), then a2, then select
  if (w<3){
    #pragma unroll
    for (int rt=0;rt<4;rt++)
      #pragma unroll
      for (int r=0;r<4;r++){
        int row=rt*16+q*4+r;
        unsigned short* pp = act + row*AST + 64*w + ln*4;
        short4v vv;
        #pragma unroll
        for (int ct=0;ct<4;ct++) vv[ct]=(short)f2bf(acc[rt][ct][r]);
        *(short4v*)pp = vv;
      }
    short8 B2[4];
    loadB<4>(B2, wq + OFF_WA2 + w*2048, lane);
    floatx4 a2[4][2];
    zeroAcc<4,2>(a2);
    runGemm<2,2>(a2, B2, aBase, 64*w);
    #pragma unroll
    for (int ct=0;ct<2;ct++){
      float b2v = cq[C_BA2 + w*32 + ct*16 + ln];
      #pragma unroll
      for (int rt=0;rt<4;rt++)
        #pragma unroll
        for (int r=0;r<4;r++){
          int row=rt*16+q*4+r;
          if (etl[row]==w) advbuf[row*32 + ct*16 + ln] = a2[rt][ct][r] + b2v;
        }
    }
  }
  __syncthreads();

  // ---- epilogue: out = v + adv - mean(adv) ----
  if (tid<64){
    float s=0;
    #pragma unroll
    for (int cc=0;cc<32;cc++){ int c=(cc+tid)&31; s+=advbuf[tid*32+c]; }  // rotated: no bank conflict
    fstat[tid].x = s*(1.f/32.f);
  }
  __syncthreads();
  {
    int row = tid>>2, c0=(tid&3)*8;
    float v = vbuf[row], m = fstat[row].x;
    float4 o0, o1;
    o0.x = v + advbuf[row*32+c0+0] - m;  o0.y = v + advbuf[row*32+c0+1] - m;
    o0.z = v + advbuf[row*32+c0+2] - m;  o0.w = v + advbuf[row*32+c0+3] - m;
    o1.x = v + advbuf[row*32+c0+4] - m;  o1.y = v + advbuf[row*32+c0+5] - m;
    o1.z = v + advbuf[row*32+c0+6] - m;  o1.w = v + advbuf[row*32+c0+7] - m;
    float* op = out + (size_t)(rowBlk+row)*32 + c0;
    *(float4*)op = o0;
    *(float4*)(op+4) = o1;
  }
}

// =====================================================================
extern "C" void kernel_launch(void* const* d_in, const int* in_sizes, int n_in,
                              void* d_out, int out_size, void* d_ws, size_t ws_size,
                              hipStream_t stream)
{
  Ptrs p;
  p.state=(const float*)d_in[0];  p.td =(const float*)d_in[1];
  p.W1 =(const float*)d_in[2];  p.b1 =(const float*)d_in[3];  p.g1 =(const float*)d_in[4];  p.be1=(const float*)d_in[5];
  p.W2 =(const float*)d_in[6];  p.b2 =(const float*)d_in[7];  p.g2 =(const float*)d_in[8];  p.be2=(const float*)d_in[9];
  p.W3 =(const float*)d_in[10]; p.b3 =(const float*)d_in[11]; p.g3 =(const float*)d_in[12]; p.be3=(const float*)d_in[13];
  p.Wv1=(const float*)d_in[14]; p.bv1=(const float*)d_in[15]; p.gv =(const float*)d_in[16]; p.bev=(const float*)d_in[17];
  p.Wv2=(const float*)d_in[18]; p.bv2=(const float*)d_in[19];
  p.Wa1=(const float*)d_in[20]; p.ba1=(const float*)d_in[21]; p.ga =(const float*)d_in[22]; p.bea=(const float*)d_in[23];
  p.Wa2=(const float*)d_in[24]; p.ba2=(const float*)d_in[25];
  p.et =(const int*)d_in[26];

  unsigned short* wq = (unsigned short*)d_ws;
  float* cq = (float*)((char*)d_ws + (size_t)NWQ*2);

  const int prepN = NWQ + NCONST;
  hipLaunchKernelGGL(prep_kernel, dim3((prepN+255)/256), dim3(256), 0, stream, p, wq, cq);
  hipLaunchKernelGGL(dqn_main, dim3(NB/TM), dim3(256), 0, stream,
                     p.state, p.td, p.et, (const unsigned short*)wq, (const float*)cq, (float*)d_out);
}

// Round 3
// 320.340 us; speedup vs baseline: 1.7442x; 1.0660x over previous
//
#include <hip/hip_runtime.h>
#include <hip/hip_bf16.h>
#include <stdint.h>

#define DEV __device__ __forceinline__

typedef __attribute__((ext_vector_type(8))) short short8;    // 8 bf16 (MFMA A/B frag)
typedef __attribute__((ext_vector_type(4))) float floatx4;   // MFMA C/D frag

constexpr int TM  = 64;     // rows per block
constexpr int NB  = 131072; // batch
constexpr int AST = 264;    // act row stride (bf16 elems)

// ---- packed bf16 weight layout in d_ws (element offsets) ----
constexpr int OFF_W1 = 0;        // 4w x 7kc x 4ct x 512   (K=224 pad of 200, N=256)
constexpr int OFF_W2 = 57344;    // 4w x 8 x 4 x 512       (K=256, N=256)
constexpr int OFF_W3 = 122880;   // 4w x 8 x 2 x 512       (K=256, N=128, SW=32)
constexpr int OFF_WH = 155648;   // 4h x 4 x 4 x 512       (K=128, N=64; h=0..2 adv, h=3 value)
constexpr int OFF_WA2= 188416;   // 3h x 2 x 2 x 512       (K=64,  N=32)
constexpr int NWQ    = 194560;

constexpr int C_B1=0, C_G1=256, C_BE1=512, C_B2=768, C_G2=1024, C_BE2=1280,
  C_B3=1536, C_G3=1664, C_BE3=1792, C_BV1=1920, C_GV=1984, C_BEV=2048,
  C_WV2=2112, C_BV2=2176, C_BA1=2177, C_GA=2369, C_BEA=2561, C_BA2=2753;
constexpr int NCONST=2849;

struct Ptrs {
  const float *state,*td,*W1,*b1,*g1,*be1,*W2,*b2,*g2,*be2,*W3,*b3,*g3,*be3,
    *Wv1,*bv1,*gv,*bev,*Wv2,*bv2,*Wa1,*ba1,*ga,*bea,*Wa2,*ba2;
  const int *et;
};

DEV unsigned short f2bf(float x){
  uint32_t u = __float_as_uint(x);
  u += 0x7fffu + ((u>>16)&1u);
  return (unsigned short)(u>>16);
}
// packed pair: a -> low16, b -> high16 (RNE), uses v_cvt_pk_bf16_f32 on gfx950
DEV uint32_t f2bf_pk(float a, float b){
  float2 f2; f2.x=a; f2.y=b;
  __hip_bfloat162 h = __float22bfloat162_rn(f2);
  union { __hip_bfloat162 h; uint32_t u; } cv; cv.h = h;
  return cv.u;
}

// =====================================================================
// prep: unchanged from R2 (verified correct)
// =====================================================================
__global__ void prep_kernel(Ptrs p, unsigned short* __restrict__ wq, float* __restrict__ cq){
  int idx = blockIdx.x*256 + threadIdx.x;
  if (idx < NWQ) {
    float v = 0.f;
    if (idx < OFF_W2) {                       // W1: k unpermuted
      int e = idx, w = e/14336, r = e%14336;
      int kc = r>>11, ct=(r>>9)&3, l=(r>>3)&63, j=r&7;
      int n = w*64 + ct*16 + (l&15);
      int k = kc*32 + (l>>4)*8 + j;
      if (k < 200) v = p.W1[k*256 + n];
    } else if (idx < OFF_W3) {                // W2: producer SW=64
      int e = idx-OFF_W2, w=e>>14, r=e&16383;
      int kc=r>>11, ct=(r>>9)&3, l=(r>>3)&63, j=r&7;
      int n = w*64 + ct*16 + (l&15);
      int k = kc*32 + (l>>4)*8 + j;
      int c = (k & ~63) + 16*(k&3) + ((k&63)>>2);
      v = p.W2[c*256 + n];
    } else if (idx < OFF_WH) {                // W3: producer SW=64, this layer SW=32
      int e = idx-OFF_W3, w=e>>13, r=e&8191;
      int kc=r>>10, ct=(r>>9)&1, l=(r>>3)&63, j=r&7;
      int n = w*32 + ct*16 + (l&15);
      int k = kc*32 + (l>>4)*8 + j;
      int c = (k & ~63) + 16*(k&3) + ((k&63)>>2);
      v = p.W3[c*128 + n];
    } else if (idx < OFF_WA2) {               // Wv1/Wa1: producer SW=32 (f)
      int e = idx-OFF_WH, h=e>>13, r=e&8191;
      int kc=r>>11, ct=(r>>9)&3, l=(r>>3)&63, j=r&7;
      int n = ct*16 + (l&15);
      int k = kc*32 + (l>>4)*8 + j;
      int c = (k & ~31) + 16*(k&1) + ((k&31)>>1);
      v = (h<3) ? p.Wa1[h*8192 + c*64 + n] : p.Wv1[c*64 + n];
    } else {                                  // Wa2: producer = head wave (64 cols)
      int e = idx-OFF_WA2, h=e>>11, r=e&2047;
      int kc=r>>10, ct=(r>>9)&1, l=(r>>3)&63, j=r&7;
      int n = ct*16 + (l&15);
      int k = kc*32 + (l>>4)*8 + j;
      int c = 16*(k&3) + (k>>2);
      v = p.Wa2[h*2048 + c*32 + n];
    }
    wq[idx] = f2bf(v);
  } else if (idx < NWQ + NCONST) {
    int ci = idx - NWQ;
    const float* src; int off;
    if      (ci < 256)  { src=p.b1;  off=ci; }
    else if (ci < 512)  { src=p.g1;  off=ci-256; }
    else if (ci < 768)  { src=p.be1; off=ci-512; }
    else if (ci < 1024) { src=p.b2;  off=ci-768; }
    else if (ci < 1280) { src=p.g2;  off=ci-1024; }
    else if (ci < 1536) { src=p.be2; off=ci-1280; }
    else if (ci < 1664) { src=p.b3;  off=ci-1536; }
    else if (ci < 1792) { src=p.g3;  off=ci-1664; }
    else if (ci < 1920) { src=p.be3; off=ci-1792; }
    else if (ci < 1984) { src=p.bv1; off=ci-1920; }
    else if (ci < 2048) { src=p.gv;  off=ci-1984; }
    else if (ci < 2112) { src=p.bev; off=ci-2048; }
    else if (ci < 2176) { src=p.Wv2; off=ci-2112; }
    else if (ci < 2177) { src=p.bv2; off=ci-2176; }
    else if (ci < 2369) { src=p.ba1; off=ci-2177; }
    else if (ci < 2561) { src=p.ga;  off=ci-2369; }
    else if (ci < 2753) { src=p.bea; off=ci-2561; }
    else                { src=p.ba2; off=ci-2753; }
    cq[ci] = src[off];
  }
}

// =====================================================================
// device helpers — all operate on ONE reused acc[4][4] (keeps AGPRs at 64)
// =====================================================================
template<int N>
DEV void loadB(short8 (&B)[N], const unsigned short* __restrict__ src, int lane){
  #pragma unroll
  for (int i=0;i<N;i++) B[i] = *(const short8*)(src + i*512 + lane*8);
}

template<int CT>
DEV void zeroAcc(floatx4 (&acc)[4][4]){
  const floatx4 z = {0.f,0.f,0.f,0.f};
  #pragma unroll
  for (int rt=0;rt<4;rt++)
    #pragma unroll
    for (int ct=0;ct<CT;ct++) acc[rt][ct]=z;
}

template<int KC,int CT>
DEV void runGemm(floatx4 (&acc)[4][4], const short8 (&B)[KC*CT],
                 const unsigned short* aBase, int aOff){
  #pragma unroll
  for (int kc=0;kc<KC;kc++){
    short8 a[4];
    #pragma unroll
    for (int rt=0;rt<4;rt++)
      a[rt] = *(const short8*)(aBase + rt*16*AST + aOff + kc*32);
    #pragma unroll
    for (int rt=0;rt<4;rt++)
      #pragma unroll
      for (int ct=0;ct<CT;ct++)
        acc[rt][ct] = __builtin_amdgcn_mfma_f32_16x16x32_bf16(a[rt], B[kc*CT+ct], acc[rt][ct], 0,0,0);
  }
}

template<int CT>
DEV void biasStatsWrite(floatx4 (&acc)[4][4], const float* __restrict__ cq, int bo, int colBase,
                        float2* pstatw, int ln, int q){
  float bias[CT];
  #pragma unroll
  for (int ct=0;ct<CT;ct++) bias[ct]=cq[bo+colBase+ct*16+ln];
  #pragma unroll
  for (int rt=0;rt<4;rt++){
    float s[4]={0,0,0,0}, ss[4]={0,0,0,0};
    #pragma unroll
    for (int ct=0;ct<CT;ct++){
      #pragma unroll
      for (int r=0;r<4;r++){
        float v=acc[rt][ct][r]+bias[ct];
        acc[rt][ct][r]=v; s[r]+=v; ss[r]+=v*v;
      }
    }
    #pragma unroll
    for (int r=0;r<4;r++){
      #pragma unroll
      for (int d=1;d<16;d<<=1){ s[r]+=__shfl_xor(s[r],d); ss[r]+=__shfl_xor(ss[r],d); }
      if (ln==0) pstatw[rt*16+q*4+r] = make_float2(s[r], ss[r]);
    }
  }
}

template<int CT>
DEV void lnWrite(floatx4 (&acc)[4][4], const float* __restrict__ cq, int go, int beo, int colBase,
                 const float2* fstat, unsigned short* act_, int ln, int q){
  float g[CT], be[CT];
  #pragma unroll
  for (int ct=0;ct<CT;ct++){ g[ct]=cq[go+colBase+ct*16+ln]; be[ct]=cq[beo+colBase+ct*16+ln]; }
  #pragma unroll
  for (int rt=0;rt<4;rt++){
    #pragma unroll
    for (int r=0;r<4;r++){
      int row=rt*16+q*4+r;
      float2 st=fstat[row];
      unsigned short* pp = act_ + row*AST + colBase + ln*CT;
      float y[CT];
      #pragma unroll
      for (int ct=0;ct<CT;ct++)
        y[ct] = fmaxf((acc[rt][ct][r]-st.x)*st.y*g[ct]+be[ct], 0.f);
      if constexpr (CT==4){
        uint2 pk; pk.x = f2bf_pk(y[0],y[1]); pk.y = f2bf_pk(y[2],y[3]);
        *(uint2*)pp = pk;
      } else {
        *(uint32_t*)pp = f2bf_pk(y[0],y[1]);
      }
    }
  }
}

// =====================================================================
// fused forward
// =====================================================================
__global__ __launch_bounds__(256,3) void dqn_main(
    const float* __restrict__ state, const float* __restrict__ td,
    const int* __restrict__ et, const unsigned short* __restrict__ wq,
    const float* __restrict__ cq, float* __restrict__ out)
{
  __shared__ __align__(16) unsigned short act[TM*AST];   // 33.8 KB
  __shared__ float2 pstat[4*64];                          // 2 KB
  __shared__ float2 fstat[64];                            // 0.5 KB
  __shared__ float  advbuf[64*32];                        // 8 KB
  __shared__ float  vbuf[64];
  __shared__ int    etl[64];

  const int tid=threadIdx.x, w=tid>>6, lane=tid&63, q=lane>>4, ln=lane&15;
  const int rowBlk = blockIdx.x*TM;

  // ---- stage x: coalesced linear copy of state (64x199), then td + zero pad ----
  {
    const float* sbase = state + (size_t)rowBlk*199;
    for (int i=tid; i<64*199; i+=256){
      float v = sbase[i];
      int row = i/199, col = i - row*199;
      act[row*AST+col] = f2bf(v);
    }
    for (int i=tid; i<64*25; i+=256){
      int row = i/25, c = 199 + (i - row*25);
      unsigned short hv = 0;
      if (c==199) hv = f2bf(td[rowBlk+row]);
      act[row*AST+c] = hv;
    }
    if (tid < 64) etl[tid] = et[rowBlk+tid];
  }
  __syncthreads();

  const unsigned short* aBase = act + ln*AST + q*8;
  floatx4 acc[4][4];   // single accumulator array reused by every segment

  // ---- L1: x(224) -> h1(256), wave cols [64w,64w+64) ----
  {
    short8 B[28];
    loadB<28>(B, wq + OFF_W1 + w*14336, lane);
    zeroAcc<4>(acc);
    runGemm<7,4>(acc, B, aBase, 0);
  }
  biasStatsWrite<4>(acc, cq, C_B1, w*64, &pstat[w*64], ln, q);
  __syncthreads();
  if (tid<64){
    float s=0, ss=0;
    #pragma unroll
    for (int ww=0;ww<4;ww++){ float2 pp=pstat[ww*64+tid]; s+=pp.x; ss+=pp.y; }
    float mu=s*(1.f/256.f), var=ss*(1.f/256.f)-mu*mu;
    fstat[tid]=make_float2(mu, rsqrtf(var+1e-5f));
  }
  __syncthreads();
  lnWrite<4>(acc, cq, C_G1, C_BE1, w*64, fstat, act, ln, q);
  __syncthreads();

  // ---- L2: h1(256) -> h2(256) ----
  {
    short8 B[32];
    loadB<32>(B, wq + OFF_W2 + w*16384, lane);
    zeroAcc<4>(acc);
    runGemm<8,4>(acc, B, aBase, 0);
  }
  biasStatsWrite<4>(acc, cq, C_B2, w*64, &pstat[w*64], ln, q);
  __syncthreads();
  if (tid<64){
    float s=0, ss=0;
    #pragma unroll
    for (int ww=0;ww<4;ww++){ float2 pp=pstat[ww*64+tid]; s+=pp.x; ss+=pp.y; }
    float mu=s*(1.f/256.f), var=ss*(1.f/256.f)-mu*mu;
    fstat[tid]=make_float2(mu, rsqrtf(var+1e-5f));
  }
  __syncthreads();
  lnWrite<4>(acc, cq, C_G2, C_BE2, w*64, fstat, act, ln, q);
  __syncthreads();

  // ---- L3: h2(256) -> f(128), wave cols [32w,32w+32) ----
  {
    short8 B[16];
    loadB<16>(B, wq + OFF_W3 + w*8192, lane);
    zeroAcc<2>(acc);
    runGemm<8,2>(acc, B, aBase, 0);
  }
  biasStatsWrite<2>(acc, cq, C_B3, w*32, &pstat[w*64], ln, q);
  __syncthreads();
  if (tid<64){
    float s=0, ss=0;
    #pragma unroll
    for (int ww=0;ww<4;ww++){ float2 pp=pstat[ww*64+tid]; s+=pp.x; ss+=pp.y; }
    float mu=s*(1.f/128.f), var=ss*(1.f/128.f)-mu*mu;
    fstat[tid]=make_float2(mu, rsqrtf(var+1e-5f));
  }
  __syncthreads();
  lnWrite<2>(acc, cq, C_G3, C_BE3, w*32, fstat, act, ln, q);
  __syncthreads();

  // ---- heads: wave w = head w (0..2 adv, 3 value). f(128) -> 64, LN in-wave ----
  {
    short8 B[16];
    loadB<16>(B, wq + OFF_WH + w*8192, lane);
    zeroAcc<4>(acc);
    runGemm<4,4>(acc, B, aBase, 0);
  }
  {
    const int bo = (w<3)? C_BA1+w*64 : C_BV1;
    const int go = (w<3)? C_GA +w*64 : C_GV;
    const int beo= (w<3)? C_BEA+w*64 : C_BEV;
    float bias[4], g[4], be[4];
    #pragma unroll
    for (int ct=0;ct<4;ct++){ bias[ct]=cq[bo+ct*16+ln]; g[ct]=cq[go+ct*16+ln]; be[ct]=cq[beo+ct*16+ln]; }
    #pragma unroll
    for (int rt=0;rt<4;rt++){
      float s[4]={0,0,0,0}, ss[4]={0,0,0,0};
      #pragma unroll
      for (int ct=0;ct<4;ct++)
        #pragma unroll
        for (int r=0;r<4;r++){
          float v=acc[rt][ct][r]+bias[ct];
          acc[rt][ct][r]=v; s[r]+=v; ss[r]+=v*v;
        }
      float mu[4], rs[4];
      #pragma unroll
      for (int r=0;r<4;r++){
        #pragma unroll
        for (int d=1;d<16;d<<=1){ s[r]+=__shfl_xor(s[r],d); ss[r]+=__shfl_xor(ss[r],d); }
        mu[r]=s[r]*(1.f/64.f);
        rs[r]=rsqrtf(ss[r]*(1.f/64.f)-mu[r]*mu[r]+1e-5f);
      }
      #pragma unroll
      for (int ct=0;ct<4;ct++)
        #pragma unroll
        for (int r=0;r<4;r++)
          acc[rt][ct][r]=fmaxf((acc[rt][ct][r]-mu[r])*rs[r]*g[ct]+be[ct], 0.f);
    }
  }

  // value head: v = v1 . Wv2 + bv2 (in regs)
  if (w==3){
    float wv[4];
    #pragma unroll
    for (int ct=0;ct<4;ct++) wv[ct]=cq[C_WV2+ct*16+ln];
    float bv2v = cq[C_BV2];
    #pragma unroll
    for (int rt=0;rt<4;rt++){
      float dd[4]={0,0,0,0};
      #pragma unroll
      for (int ct=0;ct<4;ct++)
        #pragma unroll
        for (int r=0;r<4;r++) dd[r]+=acc[rt][ct][r]*wv[ct];
      #pragma unroll
      for (int r=0;r<4;r++){
        #pragma unroll
        for (int d=1;d<16;d<<=1) dd[r]+=__shfl_xor(dd[r],d);
        if (ln==0) vbuf[rt*16+q*4+r]=dd[r]+bv2v;
      }
    }
  }
  __syncthreads();   // all f-reads complete before ha overwrites act

  // adv heads: write ha into act cols [64w,64w+64), then a2 (reuses acc), select
  if (w<3){
    #pragma unroll
    for (int rt=0;rt<4;rt++)
      #pragma unroll
      for (int r=0;r<4;r++){
        int row=rt*16+q*4+r;
        unsigned short* pp = act + row*AST + 64*w + ln*4;
        uint2 pk;
        pk.x = f2bf_pk(acc[rt][0][r], acc[rt][1][r]);
        pk.y = f2bf_pk(acc[rt][2][r], acc[rt][3][r]);
        *(uint2*)pp = pk;
      }
    short8 B2[4];
    loadB<4>(B2, wq + OFF_WA2 + w*2048, lane);
    zeroAcc<2>(acc);
    runGemm<2,2>(acc, B2, aBase, 64*w);
    #pragma unroll
    for (int ct=0;ct<2;ct++){
      float b2v = cq[C_BA2 + w*32 + ct*16 + ln];
      #pragma unroll
      for (int rt=0;rt<4;rt++)
        #pragma unroll
        for (int r=0;r<4;r++){
          int row=rt*16+q*4+r;
          if (etl[row]==w) advbuf[row*32 + ct*16 + ln] = acc[rt][ct][r] + b2v;
        }
    }
  }
  __syncthreads();

  // ---- epilogue: out = v + adv - mean(adv) ----
  if (tid<64){
    float s=0;
    #pragma unroll
    for (int cc=0;cc<32;cc++){ int c=(cc+tid)&31; s+=advbuf[tid*32+c]; }
    fstat[tid].x = s*(1.f/32.f);
  }
  __syncthreads();
  {
    int row = tid>>2, c0=(tid&3)*8;
    float v = vbuf[row], m = fstat[row].x;
    float4 o0, o1;
    o0.x = v + advbuf[row*32+c0+0] - m;  o0.y = v + advbuf[row*32+c0+1] - m;
    o0.z = v + advbuf[row*32+c0+2] - m;  o0.w = v + advbuf[row*32+c0+3] - m;
    o1.x = v + advbuf[row*32+c0+4] - m;  o1.y = v + advbuf[row*32+c0+5] - m;
    o1.z = v + advbuf[row*32+c0+6] - m;  o1.w = v + advbuf[row*32+c0+7] - m;
    float* op = out + (size_t)(rowBlk+row)*32 + c0;
    *(float4*)op = o0;
    *(float4*)(op+4) = o1;
  }
}

// =====================================================================
extern "C" void kernel_launch(void* const* d_in, const int* in_sizes, int n_in,
                              void* d_out, int out_size, void* d_ws, size_t ws_size,
                              hipStream_t stream)
{
  Ptrs p;
  p.state=(const float*)d_in[0];  p.td =(const float*)d_in[1];
  p.W1 =(const float*)d_in[2];  p.b1 =(const float*)d_in[3];  p.g1 =(const float*)d_in[4];  p.be1=(const float*)d_in[5];
  p.W2 =(const float*)d_in[6];  p.b2 =(const float*)d_in[7];  p.g2 =(const float*)d_in[8];  p.be2=(const float*)d_in[9];
  p.W3 =(const float*)d_in[10]; p.b3 =(const float*)d_in[11]; p.g3 =(const float*)d_in[12]; p.be3=(const float*)d_in[13];
  p.Wv1=(const float*)d_in[14]; p.bv1=(const float*)d_in[15]; p.gv =(const float*)d_in[16]; p.bev=(const float*)d_in[17];
  p.Wv2=(const float*)d_in[18]; p.bv2=(const float*)d_in[19];
  p.Wa1=(const float*)d_in[20]; p.ba1=(const float*)d_in[21]; p.ga =(const float*)d_in[22]; p.bea=(const float*)d_in[23];
  p.Wa2=(const float*)d_in[24]; p.ba2=(const float*)d_in[25];
  p.et =(const int*)d_in[26];

  unsigned short* wq = (unsigned short*)d_ws;
  float* cq = (float*)((char*)d_ws + (size_t)NWQ*2);

  const int prepN = NWQ + NCONST;
  hipLaunchKernelGGL(prep_kernel, dim3((prepN+255)/256), dim3(256), 0, stream, p, wq, cq);
  hipLaunchKernelGGL(dqn_main, dim3(NB/TM), dim3(256), 0, stream,
                     p.state, p.td, p.et, (const unsigned short*)wq, (const float*)cq, (float*)d_out);
}

// Round 4
// 316.647 us; speedup vs baseline: 1.7645x; 1.0117x over previous
//
#include <hip/hip_runtime.h>
#include <hip/hip_bf16.h>
#include <stdint.h>

#define DEV __device__ __forceinline__

typedef __attribute__((ext_vector_type(8))) short short8;    // 8 bf16 (MFMA A/B frag)
typedef __attribute__((ext_vector_type(4))) float floatx4;   // MFMA C/D frag

constexpr int TM  = 64;     // rows per block
constexpr int NB  = 131072; // batch
constexpr int AST = 264;    // act row stride (bf16 elems)

// ---- packed bf16 weight layout in d_ws (element offsets) ----
constexpr int OFF_W1 = 0;        // 4w x 7kc x 4ct x 512   (K=224: 199 state + td + BIAS@200)
constexpr int OFF_W2 = 57344;    // 4w x 8 x 4 x 512       (K=256, N=256)
constexpr int OFF_W3 = 122880;   // 4w x 8 x 2 x 512       (K=256, N=128, SW=32)
constexpr int OFF_WH = 155648;   // 4h x 4 x 4 x 512       (K=128, N=64; h=0..2 adv, h=3 value)
constexpr int OFF_WA2= 188416;   // 3h x 2 x 2 x 512       (K=64,  N=32)
constexpr int NWQ    = 194560;

constexpr int C_B1=0, C_G1=256, C_BE1=512, C_B2=768, C_G2=1024, C_BE2=1280,
  C_B3=1536, C_G3=1664, C_BE3=1792, C_BV1=1920, C_GV=1984, C_BEV=2048,
  C_WV2=2112, C_BV2=2176, C_BA1=2177, C_GA=2369, C_BEA=2561, C_BA2=2753;
constexpr int NCONST=2849;

struct Ptrs {
  const float *state,*td,*W1,*b1,*g1,*be1,*W2,*b2,*g2,*be2,*W3,*b3,*g3,*be3,
    *Wv1,*bv1,*gv,*bev,*Wv2,*bv2,*Wa1,*ba1,*ga,*bea,*Wa2,*ba2;
  const int *et;
};

DEV unsigned short f2bf(float x){
  uint32_t u = __float_as_uint(x);
  u += 0x7fffu + ((u>>16)&1u);
  return (unsigned short)(u>>16);
}
DEV uint32_t f2bf_pk(float a, float b){
  float2 f2; f2.x=a; f2.y=b;
  __hip_bfloat162 h = __float22bfloat162_rn(f2);
  union { __hip_bfloat162 h; uint32_t u; } cv; cv.h = h;
  return cv.u;
}

// =====================================================================
// prep: same as R2/R3 except W1 row k==200 carries b1 (bias-in-K for L1)
// =====================================================================
__global__ void prep_kernel(Ptrs p, unsigned short* __restrict__ wq, float* __restrict__ cq){
  int idx = blockIdx.x*256 + threadIdx.x;
  if (idx < NWQ) {
    float v = 0.f;
    if (idx < OFF_W2) {                       // W1 (+bias row at k=200)
      int e = idx, w = e/14336, r = e%14336;
      int kc = r>>11, ct=(r>>9)&3, l=(r>>3)&63, j=r&7;
      int n = w*64 + ct*16 + (l&15);
      int k = kc*32 + (l>>4)*8 + j;
      if (k < 200) v = p.W1[k*256 + n];
      else if (k == 200) v = p.b1[n];
    } else if (idx < OFF_W3) {                // W2: producer SW=64
      int e = idx-OFF_W2, w=e>>14, r=e&16383;
      int kc=r>>11, ct=(r>>9)&3, l=(r>>3)&63, j=r&7;
      int n = w*64 + ct*16 + (l&15);
      int k = kc*32 + (l>>4)*8 + j;
      int c = (k & ~63) + 16*(k&3) + ((k&63)>>2);
      v = p.W2[c*256 + n];
    } else if (idx < OFF_WH) {                // W3: producer SW=64, this layer SW=32
      int e = idx-OFF_W3, w=e>>13, r=e&8191;
      int kc=r>>10, ct=(r>>9)&1, l=(r>>3)&63, j=r&7;
      int n = w*32 + ct*16 + (l&15);
      int k = kc*32 + (l>>4)*8 + j;
      int c = (k & ~63) + 16*(k&3) + ((k&63)>>2);
      v = p.W3[c*128 + n];
    } else if (idx < OFF_WA2) {               // Wv1/Wa1: producer SW=32 (f)
      int e = idx-OFF_WH, h=e>>13, r=e&8191;
      int kc=r>>11, ct=(r>>9)&3, l=(r>>3)&63, j=r&7;
      int n = ct*16 + (l&15);
      int k = kc*32 + (l>>4)*8 + j;
      int c = (k & ~31) + 16*(k&1) + ((k&31)>>1);
      v = (h<3) ? p.Wa1[h*8192 + c*64 + n] : p.Wv1[c*64 + n];
    } else {                                  // Wa2: producer = head wave (64 cols)
      int e = idx-OFF_WA2, h=e>>11, r=e&2047;
      int kc=r>>10, ct=(r>>9)&1, l=(r>>3)&63, j=r&7;
      int n = ct*16 + (l&15);
      int k = kc*32 + (l>>4)*8 + j;
      int c = 16*(k&3) + (k>>2);
      v = p.Wa2[h*2048 + c*32 + n];
    }
    wq[idx] = f2bf(v);
  } else if (idx < NWQ + NCONST) {
    int ci = idx - NWQ;
    const float* src; int off;
    if      (ci < 256)  { src=p.b1;  off=ci; }
    else if (ci < 512)  { src=p.g1;  off=ci-256; }
    else if (ci < 768)  { src=p.be1; off=ci-512; }
    else if (ci < 1024) { src=p.b2;  off=ci-768; }
    else if (ci < 1280) { src=p.g2;  off=ci-1024; }
    else if (ci < 1536) { src=p.be2; off=ci-1280; }
    else if (ci < 1664) { src=p.b3;  off=ci-1536; }
    else if (ci < 1792) { src=p.g3;  off=ci-1664; }
    else if (ci < 1920) { src=p.be3; off=ci-1792; }
    else if (ci < 1984) { src=p.bv1; off=ci-1920; }
    else if (ci < 2048) { src=p.gv;  off=ci-1984; }
    else if (ci < 2112) { src=p.bev; off=ci-2048; }
    else if (ci < 2176) { src=p.Wv2; off=ci-2112; }
    else if (ci < 2177) { src=p.bv2; off=ci-2176; }
    else if (ci < 2369) { src=p.ba1; off=ci-2177; }
    else if (ci < 2561) { src=p.ga;  off=ci-2369; }
    else if (ci < 2753) { src=p.bea; off=ci-2561; }
    else                { src=p.ba2; off=ci-2753; }
    cq[ci] = src[off];
  }
}

// =====================================================================
// device helpers
// =====================================================================
template<int CT>
DEV void loadBslice(short8* Bb, const unsigned short* __restrict__ src, int lane){
  #pragma unroll
  for (int ct=0;ct<CT;ct++) Bb[ct] = *(const short8*)(src + ct*512 + lane*8);
}

template<int CT>
DEV void zeroAcc(floatx4 (&acc)[4][4]){
  const floatx4 z = {0.f,0.f,0.f,0.f};
  #pragma unroll
  for (int rt=0;rt<4;rt++)
    #pragma unroll
    for (int ct=0;ct<CT;ct++) acc[rt][ct]=z;
}

// explicit register double-buffered B pipeline: Ba holds kc=0 (preloaded);
// loads for kc+1 issue BEFORE the 16 MFMAs of kc (≈310cy of matrix work
// hides the L2 hit). Last layer's epilogue prefetches the next layer's kc0.
template<int KC,int CT>
DEV void gemmPipe(floatx4 (&acc)[4][4], short8 (&Ba)[4], short8 (&Bbuf)[4],
                  const unsigned short* __restrict__ wsrc,
                  const unsigned short* aBase, int aOff, int lane){
  #pragma unroll
  for (int kc=0;kc<KC;kc++){
    short8* cur = (kc&1)? Bbuf : Ba;
    short8* nxt = (kc&1)? Ba   : Bbuf;
    if (kc+1<KC) loadBslice<CT>(nxt, wsrc + (kc+1)*CT*512, lane);
    short8 a[4];
    #pragma unroll
    for (int rt=0;rt<4;rt++)
      a[rt] = *(const short8*)(aBase + rt*16*AST + aOff + kc*32);
    #pragma unroll
    for (int rt=0;rt<4;rt++)
      #pragma unroll
      for (int ct=0;ct<CT;ct++)
        acc[rt][ct] = __builtin_amdgcn_mfma_f32_16x16x32_bf16(a[rt], cur[ct], acc[rt][ct], 0,0,0);
  }
}

// stats pass: reads acc ONCE (no write-back); bias optional (L1 has it in K)
template<int CT,bool BIAS>
DEV void statsPhase(const floatx4 (&acc)[4][4], const float* __restrict__ cq, int bo, int colBase,
                    float2* pstatw, int ln, int q, float (&bias)[4]){
  if constexpr (BIAS){
    #pragma unroll
    for (int ct=0;ct<CT;ct++) bias[ct]=cq[bo+colBase+ct*16+ln];
  } else {
    #pragma unroll
    for (int ct=0;ct<CT;ct++) bias[ct]=0.f;
  }
  #pragma unroll
  for (int rt=0;rt<4;rt++){
    float s[4]={0,0,0,0}, ss[4]={0,0,0,0};
    #pragma unroll
    for (int ct=0;ct<CT;ct++){
      #pragma unroll
      for (int r=0;r<4;r++){
        float v=acc[rt][ct][r]+bias[ct];
        s[r]+=v; ss[r]+=v*v;
      }
    }
    #pragma unroll
    for (int r=0;r<4;r++){
      #pragma unroll
      for (int d=1;d<16;d<<=1){ s[r]+=__shfl_xor(s[r],d); ss[r]+=__shfl_xor(ss[r],d); }
      if (ln==0) pstatw[rt*16+q*4+r] = make_float2(s[r], ss[r]);
    }
  }
}

// LN apply + relu + packed bf16 act write (re-adds bias in-flight)
template<int CT>
DEV void lnWrite(const floatx4 (&acc)[4][4], const float* __restrict__ cq, int go, int beo, int colBase,
                 const float2* fstat, unsigned short* act_, int ln, int q, const float (&bias)[4]){
  float g[CT], be[CT];
  #pragma unroll
  for (int ct=0;ct<CT;ct++){ g[ct]=cq[go+colBase+ct*16+ln]; be[ct]=cq[beo+colBase+ct*16+ln]; }
  #pragma unroll
  for (int rt=0;rt<4;rt++){
    #pragma unroll
    for (int r=0;r<4;r++){
      int row=rt*16+q*4+r;
      float2 st=fstat[row];
      unsigned short* pp = act_ + row*AST + colBase + ln*CT;
      float y[CT];
      #pragma unroll
      for (int ct=0;ct<CT;ct++)
        y[ct] = fmaxf((acc[rt][ct][r]+bias[ct]-st.x)*st.y*g[ct]+be[ct], 0.f);
      if constexpr (CT==4){
        uint2 pk; pk.x = f2bf_pk(y[0],y[1]); pk.y = f2bf_pk(y[2],y[3]);
        *(uint2*)pp = pk;
      } else {
        *(uint32_t*)pp = f2bf_pk(y[0],y[1]);
      }
    }
  }
}

DEV void fstatReduce(const float2* pstat, float2* fstat, int tid, float invN){
  if (tid<64){
    float s=0, ss=0;
    #pragma unroll
    for (int ww=0;ww<4;ww++){ float2 pp=pstat[ww*64+tid]; s+=pp.x; ss+=pp.y; }
    float mu=s*invN, var=ss*invN-mu*mu;
    fstat[tid]=make_float2(mu, rsqrtf(var+1e-5f));
  }
}

// =====================================================================
// fused forward
// =====================================================================
__global__ __launch_bounds__(256,3) void dqn_main(
    const float* __restrict__ state, const float* __restrict__ td,
    const int* __restrict__ et, const unsigned short* __restrict__ wq,
    const float* __restrict__ cq, float* __restrict__ out)
{
  __shared__ __align__(16) unsigned short act[TM*AST];   // 33.8 KB
  __shared__ float2 pstat[4*64];                          // 2 KB
  __shared__ float2 fstat[64];                            // 0.5 KB
  __shared__ float  advbuf[64*32];                        // 8 KB
  __shared__ float  vbuf[64];
  __shared__ int    etl[64];

  const int tid=threadIdx.x, w=tid>>6, lane=tid&63, q=lane>>4, ln=lane&15;
  const int rowBlk = blockIdx.x*TM;

  const unsigned short* wqL1 = wq + OFF_W1 + w*14336;
  const unsigned short* wqL2 = wq + OFF_W2 + w*16384;
  const unsigned short* wqL3 = wq + OFF_W3 + w*8192;
  const unsigned short* wqH  = wq + OFF_WH + w*8192;
  const unsigned short* wqA2 = wq + OFF_WA2 + w*2048;

  short8 Ba[4], Bbuf[4];
  loadBslice<4>(Ba, wqL1, lane);        // L1 kc0 in flight during staging

  // ---- stage x = [state(199) | td@199 | 1.0@200 (bias slot) | 0 pad] ----
  {
    const float* sbase = state + (size_t)rowBlk*199;
    for (int i=tid; i<64*199; i+=256){
      float v = sbase[i];
      int row = i/199, col = i - row*199;
      act[row*AST+col] = f2bf(v);
    }
    for (int i=tid; i<64*25; i+=256){
      int row = i/25, c = 199 + (i - row*25);
      unsigned short hv = 0;
      if (c==199) hv = f2bf(td[rowBlk+row]);
      else if (c==200) hv = 0x3F80u;    // bf16(1.0) — multiplies W1's bias row
      act[row*AST+c] = hv;
    }
    if (tid < 64) etl[tid] = et[rowBlk+tid];
  }
  __syncthreads();

  const unsigned short* aBase = act + ln*AST + q*8;
  floatx4 acc[4][4];
  float bias[4];

  // ---- L1: x(224 incl bias) -> h1(256), wave cols [64w,64w+64) ----
  zeroAcc<4>(acc);
  gemmPipe<7,4>(acc, Ba, Bbuf, wqL1, aBase, 0, lane);
  loadBslice<4>(Ba, wqL2, lane);        // prefetch L2 kc0 behind epilogue
  statsPhase<4,false>(acc, cq, 0, w*64, &pstat[w*64], ln, q, bias);
  __syncthreads();
  fstatReduce(pstat, fstat, tid, 1.f/256.f);
  __syncthreads();
  lnWrite<4>(acc, cq, C_G1, C_BE1, w*64, fstat, act, ln, q, bias);
  __syncthreads();

  // ---- L2: h1(256) -> h2(256) ----
  zeroAcc<4>(acc);
  gemmPipe<8,4>(acc, Ba, Bbuf, wqL2, aBase, 0, lane);
  loadBslice<2>(Ba, wqL3, lane);        // prefetch L3 kc0
  statsPhase<4,true>(acc, cq, C_B2, w*64, &pstat[w*64], ln, q, bias);
  __syncthreads();
  fstatReduce(pstat, fstat, tid, 1.f/256.f);
  __syncthreads();
  lnWrite<4>(acc, cq, C_G2, C_BE2, w*64, fstat, act, ln, q, bias);
  __syncthreads();

  // ---- L3: h2(256) -> f(128), wave cols [32w,32w+32) ----
  zeroAcc<2>(acc);
  gemmPipe<8,2>(acc, Ba, Bbuf, wqL3, aBase, 0, lane);
  loadBslice<4>(Ba, wqH, lane);         // prefetch head kc0
  statsPhase<2,true>(acc, cq, C_B3, w*32, &pstat[w*64], ln, q, bias);
  __syncthreads();
  fstatReduce(pstat, fstat, tid, 1.f/128.f);
  __syncthreads();
  lnWrite<2>(acc, cq, C_G3, C_BE3, w*32, fstat, act, ln, q, bias);
  __syncthreads();

  // ---- heads: wave w = head w (0..2 adv, 3 value). f(128) -> 64, LN in-wave ----
  zeroAcc<4>(acc);
  gemmPipe<4,4>(acc, Ba, Bbuf, wqH, aBase, 0, lane);
  if (w<3) loadBslice<2>(Ba, wqA2, lane);  // prefetch a2 kc0
  {
    const int bo = (w<3)? C_BA1+w*64 : C_BV1;
    const int go = (w<3)? C_GA +w*64 : C_GV;
    const int beo= (w<3)? C_BEA+w*64 : C_BEV;
    float bi[4], g[4], be[4];
    #pragma unroll
    for (int ct=0;ct<4;ct++){ bi[ct]=cq[bo+ct*16+ln]; g[ct]=cq[go+ct*16+ln]; be[ct]=cq[beo+ct*16+ln]; }
    float wv[4]; float bv2v = 0.f;
    if (w==3){
      #pragma unroll
      for (int ct=0;ct<4;ct++) wv[ct]=cq[C_WV2+ct*16+ln];
      bv2v = cq[C_BV2];
    }
    #pragma unroll
    for (int rt=0;rt<4;rt++){
      float y[4][4];   // [ct][r]
      float s[4]={0,0,0,0}, ss[4]={0,0,0,0};
      #pragma unroll
      for (int ct=0;ct<4;ct++)
        #pragma unroll
        for (int r=0;r<4;r++){
          float v=acc[rt][ct][r]+bi[ct];
          y[ct][r]=v; s[r]+=v; ss[r]+=v*v;
        }
      float mu[4], rs[4];
      #pragma unroll
      for (int r=0;r<4;r++){
        #pragma unroll
        for (int d=1;d<16;d<<=1){ s[r]+=__shfl_xor(s[r],d); ss[r]+=__shfl_xor(ss[r],d); }
        mu[r]=s[r]*(1.f/64.f);
        rs[r]=rsqrtf(ss[r]*(1.f/64.f)-mu[r]*mu[r]+1e-5f);
      }
      #pragma unroll
      for (int ct=0;ct<4;ct++)
        #pragma unroll
        for (int r=0;r<4;r++)
          y[ct][r]=fmaxf((y[ct][r]-mu[r])*rs[r]*g[ct]+be[ct], 0.f);

      if (w==3){
        float dd[4]={0,0,0,0};
        #pragma unroll
        for (int ct=0;ct<4;ct++)
          #pragma unroll
          for (int r=0;r<4;r++) dd[r]+=y[ct][r]*wv[ct];
        #pragma unroll
        for (int r=0;r<4;r++){
          #pragma unroll
          for (int d=1;d<16;d<<=1) dd[r]+=__shfl_xor(dd[r],d);
          if (ln==0) vbuf[rt*16+q*4+r]=dd[r]+bv2v;
        }
      } else {
        #pragma unroll
        for (int r=0;r<4;r++){
          int row=rt*16+q*4+r;
          unsigned short* pp = act + row*AST + 64*w + ln*4;
          uint2 pk;
          pk.x = f2bf_pk(y[0][r], y[1][r]);
          pk.y = f2bf_pk(y[2][r], y[3][r]);
          *(uint2*)pp = pk;     // safe: heads read f (cols 0..127) via regs already
        }
      }
    }
  }
  __syncthreads();   // ha writes visible; f no longer needed

  // adv heads second matmul + select
  if (w<3){
    zeroAcc<2>(acc);
    gemmPipe<2,2>(acc, Ba, Bbuf, wqA2, aBase, 64*w, lane);
    #pragma unroll
    for (int ct=0;ct<2;ct++){
      float b2v = cq[C_BA2 + w*32 + ct*16 + ln];
      #pragma unroll
      for (int rt=0;rt<4;rt++)
        #pragma unroll
        for (int r=0;r<4;r++){
          int row=rt*16+q*4+r;
          if (etl[row]==w) advbuf[row*32 + ct*16 + ln] = acc[rt][ct][r] + b2v;
        }
    }
  }
  __syncthreads();

  // ---- epilogue: out = v + adv - mean(adv) ----
  if (tid<64){
    float s=0;
    #pragma unroll
    for (int cc=0;cc<32;cc++){ int c=(cc+tid)&31; s+=advbuf[tid*32+c]; }
    fstat[tid].x = s*(1.f/32.f);
  }
  __syncthreads();
  {
    int row = tid>>2, c0=(tid&3)*8;
    float v = vbuf[row], m = fstat[row].x;
    float4 o0, o1;
    o0.x = v + advbuf[row*32+c0+0] - m;  o0.y = v + advbuf[row*32+c0+1] - m;
    o0.z = v + advbuf[row*32+c0+2] - m;  o0.w = v + advbuf[row*32+c0+3] - m;
    o1.x = v + advbuf[row*32+c0+4] - m;  o1.y = v + advbuf[row*32+c0+5] - m;
    o1.z = v + advbuf[row*32+c0+6] - m;  o1.w = v + advbuf[row*32+c0+7] - m;
    float* op = out + (size_t)(rowBlk+row)*32 + c0;
    *(float4*)op = o0;
    *(float4*)(op+4) = o1;
  }
}

// =====================================================================
extern "C" void kernel_launch(void* const* d_in, const int* in_sizes, int n_in,
                              void* d_out, int out_size, void* d_ws, size_t ws_size,
                              hipStream_t stream)
{
  Ptrs p;
  p.state=(const float*)d_in[0];  p.td =(const float*)d_in[1];
  p.W1 =(const float*)d_in[2];  p.b1 =(const float*)d_in[3];  p.g1 =(const float*)d_in[4];  p.be1=(const float*)d_in[5];
  p.W2 =(const float*)d_in[6];  p.b2 =(const float*)d_in[7];  p.g2 =(const float*)d_in[8];  p.be2=(const float*)d_in[9];
  p.W3 =(const float*)d_in[10]; p.b3 =(const float*)d_in[11]; p.g3 =(const float*)d_in[12]; p.be3=(const float*)d_in[13];
  p.Wv1=(const float*)d_in[14]; p.bv1=(const float*)d_in[15]; p.gv =(const float*)d_in[16]; p.bev=(const float*)d_in[17];
  p.Wv2=(const float*)d_in[18]; p.bv2=(const float*)d_in[19];
  p.Wa1=(const float*)d_in[20]; p.ba1=(const float*)d_in[21]; p.ga =(const float*)d_in[22]; p.bea=(const float*)d_in[23];
  p.Wa2=(const float*)d_in[24]; p.ba2=(const float*)d_in[25];
  p.et =(const int*)d_in[26];

  unsigned short* wq = (unsigned short*)d_ws;
  float* cq = (float*)((char*)d_ws + (size_t)NWQ*2);

  const int prepN = NWQ + NCONST;
  hipLaunchKernelGGL(prep_kernel, dim3((prepN+255)/256), dim3(256), 0, stream, p, wq, cq);
  hipLaunchKernelGGL(dqn_main, dim3(NB/TM), dim3(256), 0, stream,
                     p.state, p.td, p.et, (const unsigned short*)wq, (const float*)cq, (float*)d_out);
}

// Round 5
// 310.161 us; speedup vs baseline: 1.8014x; 1.0209x over previous
//
#include <hip/hip_runtime.h>
#include <hip/hip_bf16.h>
#include <stdint.h>

#define DEV __device__ __forceinline__

typedef __attribute__((ext_vector_type(8))) short short8;    // 8 bf16 (MFMA A/B frag)
typedef __attribute__((ext_vector_type(4))) float floatx4;   // MFMA C/D frag

constexpr int TM  = 64;     // rows per block
constexpr int NB  = 131072; // batch
constexpr int AST = 264;    // act row stride (bf16 elems)

// ---- packed bf16 weight layout in d_ws (element offsets) ----
constexpr int OFF_W1 = 0;        // 4w x 7kc x 4ct x 512   (K=224: 199 state + td + BIAS@200)
constexpr int OFF_W2 = 57344;    // 4w x 8 x 4 x 512       (K=256, N=256)
constexpr int OFF_W3 = 122880;   // 4w x 8 x 2 x 512       (K=256, N=128, SW=32)
constexpr int OFF_WH = 155648;   // 4h x 4 x 4 x 512       (K=128, N=64; h=0..2 adv, h=3 value)
constexpr int OFF_WA2= 188416;   // 3h x 2 x 2 x 512       (K=64,  N=32)
constexpr int NWQ    = 194560;

constexpr int C_B1=0, C_G1=256, C_BE1=512, C_B2=768, C_G2=1024, C_BE2=1280,
  C_B3=1536, C_G3=1664, C_BE3=1792, C_BV1=1920, C_GV=1984, C_BEV=2048,
  C_WV2=2112, C_BV2=2176, C_BA1=2177, C_GA=2369, C_BEA=2561, C_BA2=2753;
constexpr int NCONST=2849;

struct Ptrs {
  const float *state,*td,*W1,*b1,*g1,*be1,*W2,*b2,*g2,*be2,*W3,*b3,*g3,*be3,
    *Wv1,*bv1,*gv,*bev,*Wv2,*bv2,*Wa1,*ba1,*ga,*bea,*Wa2,*ba2;
  const int *et;
};

DEV unsigned short f2bf(float x){
  uint32_t u = __float_as_uint(x);
  u += 0x7fffu + ((u>>16)&1u);
  return (unsigned short)(u>>16);
}
DEV uint32_t f2bf_pk(float a, float b){
  float2 f2; f2.x=a; f2.y=b;
  __hip_bfloat162 h = __float22bfloat162_rn(f2);
  union { __hip_bfloat162 h; uint32_t u; } cv; cv.h = h;
  return cv.u;
}

// =====================================================================
// prep: quantize + transpose + pack weights (W1 carries b1 at k==200)
// =====================================================================
__global__ void prep_kernel(Ptrs p, unsigned short* __restrict__ wq, float* __restrict__ cq){
  int idx = blockIdx.x*256 + threadIdx.x;
  if (idx < NWQ) {
    float v = 0.f;
    if (idx < OFF_W2) {                       // W1 (+bias row at k=200)
      int e = idx, w = e/14336, r = e%14336;
      int kc = r>>11, ct=(r>>9)&3, l=(r>>3)&63, j=r&7;
      int n = w*64 + ct*16 + (l&15);
      int k = kc*32 + (l>>4)*8 + j;
      if (k < 200) v = p.W1[k*256 + n];
      else if (k == 200) v = p.b1[n];
    } else if (idx < OFF_W3) {                // W2: producer SW=64
      int e = idx-OFF_W2, w=e>>14, r=e&16383;
      int kc=r>>11, ct=(r>>9)&3, l=(r>>3)&63, j=r&7;
      int n = w*64 + ct*16 + (l&15);
      int k = kc*32 + (l>>4)*8 + j;
      int c = (k & ~63) + 16*(k&3) + ((k&63)>>2);
      v = p.W2[c*256 + n];
    } else if (idx < OFF_WH) {                // W3: producer SW=64, this layer SW=32
      int e = idx-OFF_W3, w=e>>13, r=e&8191;
      int kc=r>>10, ct=(r>>9)&1, l=(r>>3)&63, j=r&7;
      int n = w*32 + ct*16 + (l&15);
      int k = kc*32 + (l>>4)*8 + j;
      int c = (k & ~63) + 16*(k&3) + ((k&63)>>2);
      v = p.W3[c*128 + n];
    } else if (idx < OFF_WA2) {               // Wv1/Wa1: producer SW=32 (f)
      int e = idx-OFF_WH, h=e>>13, r=e&8191;
      int kc=r>>11, ct=(r>>9)&3, l=(r>>3)&63, j=r&7;
      int n = ct*16 + (l&15);
      int k = kc*32 + (l>>4)*8 + j;
      int c = (k & ~31) + 16*(k&1) + ((k&31)>>1);
      v = (h<3) ? p.Wa1[h*8192 + c*64 + n] : p.Wv1[c*64 + n];
    } else {                                  // Wa2: producer = head wave (64 cols)
      int e = idx-OFF_WA2, h=e>>11, r=e&2047;
      int kc=r>>10, ct=(r>>9)&1, l=(r>>3)&63, j=r&7;
      int n = ct*16 + (l&15);
      int k = kc*32 + (l>>4)*8 + j;
      int c = 16*(k&3) + (k>>2);
      v = p.Wa2[h*2048 + c*32 + n];
    }
    wq[idx] = f2bf(v);
  } else if (idx < NWQ + NCONST) {
    int ci = idx - NWQ;
    const float* src; int off;
    if      (ci < 256)  { src=p.b1;  off=ci; }
    else if (ci < 512)  { src=p.g1;  off=ci-256; }
    else if (ci < 768)  { src=p.be1; off=ci-512; }
    else if (ci < 1024) { src=p.b2;  off=ci-768; }
    else if (ci < 1280) { src=p.g2;  off=ci-1024; }
    else if (ci < 1536) { src=p.be2; off=ci-1280; }
    else if (ci < 1664) { src=p.b3;  off=ci-1536; }
    else if (ci < 1792) { src=p.g3;  off=ci-1664; }
    else if (ci < 1920) { src=p.be3; off=ci-1792; }
    else if (ci < 1984) { src=p.bv1; off=ci-1920; }
    else if (ci < 2048) { src=p.gv;  off=ci-1984; }
    else if (ci < 2112) { src=p.bev; off=ci-2048; }
    else if (ci < 2176) { src=p.Wv2; off=ci-2112; }
    else if (ci < 2177) { src=p.bv2; off=ci-2176; }
    else if (ci < 2369) { src=p.ba1; off=ci-2177; }
    else if (ci < 2561) { src=p.ga;  off=ci-2369; }
    else if (ci < 2753) { src=p.bea; off=ci-2561; }
    else                { src=p.ba2; off=ci-2753; }
    cq[ci] = src[off];
  }
}

// =====================================================================
// device helpers (R3-proven forms; no pointer ping-pong!)
// =====================================================================
template<int N>
DEV void loadB(short8 (&B)[N], const unsigned short* __restrict__ src, int lane){
  #pragma unroll
  for (int i=0;i<N;i++) B[i] = *(const short8*)(src + i*512 + lane*8);
}

template<int CT>
DEV void zeroAcc(floatx4 (&acc)[4][4]){
  const floatx4 z = {0.f,0.f,0.f,0.f};
  #pragma unroll
  for (int rt=0;rt<4;rt++)
    #pragma unroll
    for (int ct=0;ct<CT;ct++) acc[rt][ct]=z;
}

template<int KC,int CT>
DEV void runGemm(floatx4 (&acc)[4][4], const short8 (&B)[KC*CT],
                 const unsigned short* aBase, int aOff){
  #pragma unroll
  for (int kc=0;kc<KC;kc++){
    short8 a[4];
    #pragma unroll
    for (int rt=0;rt<4;rt++)
      a[rt] = *(const short8*)(aBase + rt*16*AST + aOff + kc*32);
    #pragma unroll
    for (int rt=0;rt<4;rt++)
      #pragma unroll
      for (int ct=0;ct<CT;ct++)
        acc[rt][ct] = __builtin_amdgcn_mfma_f32_16x16x32_bf16(a[rt], B[kc*CT+ct], acc[rt][ct], 0,0,0);
  }
}

// bias + per-row partials (s,ss) over this wave's cols -> LDS atomic accumulate
template<int CT,bool BIAS>
DEV void statsAtomic(const floatx4 (&acc)[4][4], const float* __restrict__ cq, int bo, int colBase,
                     float* sbuf, float* ssbuf, int ln, int q, float (&bias)[4]){
  #pragma unroll
  for (int ct=0;ct<CT;ct++) bias[ct] = BIAS ? cq[bo+colBase+ct*16+ln] : 0.f;
  #pragma unroll
  for (int rt=0;rt<4;rt++){
    float s[4]={0,0,0,0}, ss[4]={0,0,0,0};
    #pragma unroll
    for (int ct=0;ct<CT;ct++){
      #pragma unroll
      for (int r=0;r<4;r++){
        float v=acc[rt][ct][r]+bias[ct];
        s[r]+=v; ss[r]+=v*v;
      }
    }
    #pragma unroll
    for (int r=0;r<4;r++){
      #pragma unroll
      for (int d=1;d<16;d<<=1){ s[r]+=__shfl_xor(s[r],d); ss[r]+=__shfl_xor(ss[r],d); }
      if (ln==0){
        int row = rt*16+q*4+r;
        atomicAdd(&sbuf[row],  s[r]);     // ds_add_f32
        atomicAdd(&ssbuf[row], ss[r]);
      }
    }
  }
}

// LN apply + relu + packed bf16 act write; per-lane rsqrt from sstat
template<int CT>
DEV void lnWrite(const floatx4 (&acc)[4][4], const float* __restrict__ cq, int go, int beo, int colBase,
                 const float* sbuf, const float* ssbuf, float invN,
                 unsigned short* act_, int ln, int q, const float (&bias)[4]){
  float g[CT], be[CT];
  #pragma unroll
  for (int ct=0;ct<CT;ct++){ g[ct]=cq[go+colBase+ct*16+ln]; be[ct]=cq[beo+colBase+ct*16+ln]; }
  #pragma unroll
  for (int rt=0;rt<4;rt++){
    floatx4 sv  = *(const floatx4*)&sbuf [rt*16+q*4];
    floatx4 ssv = *(const floatx4*)&ssbuf[rt*16+q*4];
    #pragma unroll
    for (int r=0;r<4;r++){
      float mu = sv[r]*invN;
      float rs = rsqrtf(ssv[r]*invN - mu*mu + 1e-5f);
      int row=rt*16+q*4+r;
      unsigned short* pp = act_ + row*AST + colBase + ln*CT;
      float y[CT];
      #pragma unroll
      for (int ct=0;ct<CT;ct++)
        y[ct] = fmaxf((acc[rt][ct][r]+bias[ct]-mu)*rs*g[ct]+be[ct], 0.f);
      if constexpr (CT==4){
        uint2 pk; pk.x = f2bf_pk(y[0],y[1]); pk.y = f2bf_pk(y[2],y[3]);
        *(uint2*)pp = pk;
      } else {
        *(uint32_t*)pp = f2bf_pk(y[0],y[1]);
      }
    }
  }
}

// =====================================================================
// fused forward: 8 barriers, no single-wave phases, direct global epilogue
// =====================================================================
__global__ __launch_bounds__(256,4) void dqn_main(
    const float* __restrict__ state, const float* __restrict__ td,
    const int* __restrict__ et, const unsigned short* __restrict__ wq,
    const float* __restrict__ cq, float* __restrict__ out)
{
  __shared__ __align__(16) unsigned short act[TM*AST];   // 33 KB
  __shared__ float sstat[2][2][64];                       // [pp][s/ss][row] 1 KB
  __shared__ float vbuf[64];
  __shared__ int   etl[64];

  const int tid=threadIdx.x, w=tid>>6, lane=tid&63, q=lane>>4, ln=lane&15;
  const int rowBlk = blockIdx.x*TM;

  // ---- stage x = [state(199) | td@199 | 1.0@200 | 0 pad]; zero both sstat pp ----
  {
    ((float*)sstat)[tid] = 0.f;    // 256 floats, one per thread
    const float* sbase = state + (size_t)rowBlk*199;
    for (int i=tid; i<64*199; i+=256){
      float v = sbase[i];
      int row = i/199, col = i - row*199;      // compiler magic-div
      act[row*AST+col] = f2bf(v);
    }
    for (int i=tid; i<64*32; i+=256){
      int row = i>>5, c = 199 + (i&31);
      unsigned short hv = 0;
      if (c==199) hv = f2bf(td[rowBlk+row]);
      else if (c==200) hv = 0x3F80u;           // bf16(1.0) * W1 bias row
      act[row*AST+c] = hv;
    }
    if (tid < 64) etl[tid] = et[rowBlk+tid];
  }
  __syncthreads();                                        // B1

  const unsigned short* aBase = act + ln*AST + q*8;
  floatx4 acc[4][4];
  float bias[4];

  // ---- L1: x(224 incl bias row) -> h1(256); stats pp0 ----
  {
    short8 B[28];
    loadB<28>(B, wq + OFF_W1 + w*14336, lane);
    zeroAcc<4>(acc);
    runGemm<7,4>(acc, B, aBase, 0);
  }
  statsAtomic<4,false>(acc, cq, 0, w*64, sstat[0][0], sstat[0][1], ln, q, bias);
  __syncthreads();                                        // B2
  lnWrite<4>(acc, cq, C_G1, C_BE1, w*64, sstat[0][0], sstat[0][1], 1.f/256.f, act, ln, q, bias);
  __syncthreads();                                        // B3

  // ---- L2: h1(256) -> h2(256); stats pp1 ----
  {
    short8 B[32];
    loadB<32>(B, wq + OFF_W2 + w*16384, lane);
    zeroAcc<4>(acc);
    runGemm<8,4>(acc, B, aBase, 0);
  }
  statsAtomic<4,true>(acc, cq, C_B2, w*64, sstat[1][0], sstat[1][1], ln, q, bias);
  __syncthreads();                                        // B4
  if (tid < 128) ((float*)sstat[0])[tid] = 0.f;           // re-zero pp0 (consumers done pre-B3)
  lnWrite<4>(acc, cq, C_G2, C_BE2, w*64, sstat[1][0], sstat[1][1], 1.f/256.f, act, ln, q, bias);
  __syncthreads();                                        // B5

  // ---- L3: h2(256) -> f(128), wave cols [32w,32w+32); stats pp0 ----
  {
    short8 B[16];
    loadB<16>(B, wq + OFF_W3 + w*8192, lane);
    zeroAcc<2>(acc);
    runGemm<8,2>(acc, B, aBase, 0);
  }
  statsAtomic<2,true>(acc, cq, C_B3, w*32, sstat[0][0], sstat[0][1], ln, q, bias);
  __syncthreads();                                        // B6
  lnWrite<2>(acc, cq, C_G3, C_BE3, w*32, sstat[0][0], sstat[0][1], 1.f/128.f, act, ln, q, bias);
  __syncthreads();                                        // B7

  // ---- heads: wave w = head w (0..2 adv, 3 value). f(128)->64, LN in-wave ----
  {
    short8 B[16];
    loadB<16>(B, wq + OFF_WH + w*8192, lane);
    zeroAcc<4>(acc);
    runGemm<4,4>(acc, B, aBase, 0);
  }
  {
    const int bo = (w<3)? C_BA1+w*64 : C_BV1;
    const int go = (w<3)? C_GA +w*64 : C_GV;
    const int beo= (w<3)? C_BEA+w*64 : C_BEV;
    float bi[4], g[4], be[4];
    #pragma unroll
    for (int ct=0;ct<4;ct++){ bi[ct]=cq[bo+ct*16+ln]; g[ct]=cq[go+ct*16+ln]; be[ct]=cq[beo+ct*16+ln]; }
    float wv[4]; float bv2v = 0.f;
    if (w==3){
      #pragma unroll
      for (int ct=0;ct<4;ct++) wv[ct]=cq[C_WV2+ct*16+ln];
      bv2v = cq[C_BV2];
    }
    #pragma unroll
    for (int rt=0;rt<4;rt++){
      float y[4][4];   // [ct][r]
      float s[4]={0,0,0,0}, ss[4]={0,0,0,0};
      #pragma unroll
      for (int ct=0;ct<4;ct++)
        #pragma unroll
        for (int r=0;r<4;r++){
          float v=acc[rt][ct][r]+bi[ct];
          y[ct][r]=v; s[r]+=v; ss[r]+=v*v;
        }
      #pragma unroll
      for (int r=0;r<4;r++){
        #pragma unroll
        for (int d=1;d<16;d<<=1){ s[r]+=__shfl_xor(s[r],d); ss[r]+=__shfl_xor(ss[r],d); }
        float mu=s[r]*(1.f/64.f);
        float rs=rsqrtf(ss[r]*(1.f/64.f)-mu*mu+1e-5f);
        #pragma unroll
        for (int ct=0;ct<4;ct++)
          y[ct][r]=fmaxf((y[ct][r]-mu)*rs*g[ct]+be[ct], 0.f);
      }

      if (w==3){
        float dd[4]={0,0,0,0};
        #pragma unroll
        for (int ct=0;ct<4;ct++)
          #pragma unroll
          for (int r=0;r<4;r++) dd[r]+=y[ct][r]*wv[ct];
        #pragma unroll
        for (int r=0;r<4;r++){
          #pragma unroll
          for (int d=1;d<16;d<<=1) dd[r]+=__shfl_xor(dd[r],d);
          if (ln==0) vbuf[rt*16+q*4+r]=dd[r]+bv2v;
        }
      } else {
        // pack ha into act cols written AFTER B8 is unnecessary for w<2, but
        // w=2 would overwrite f; keep uniform: stash y and write post-B8.
        #pragma unroll
        for (int r=0;r<4;r++){
          int row=rt*16+q*4+r;
          // defer: write below after barrier
          // store into registers is y itself; we write after B8 using y
          (void)row;
        }
      }
      // persist y for adv waves by writing after barrier: we need y beyond
      // this rt-iteration, so for adv waves write to act NOW is unsafe (f in
      // use). Instead accumulate into acc (reuse as storage).
      if (w<3){
        #pragma unroll
        for (int ct=0;ct<4;ct++)
          #pragma unroll
          for (int r=0;r<4;r++) acc[rt][ct][r]=y[ct][r];
      }
    }
  }
  __syncthreads();                                        // B8: head f-reads done; vbuf visible

  // adv heads: write ha (from acc) into act cols [64w,64w+64), a2 GEMM, direct out
  if (w<3){
    #pragma unroll
    for (int rt=0;rt<4;rt++)
      #pragma unroll
      for (int r=0;r<4;r++){
        int row=rt*16+q*4+r;
        unsigned short* pp = act + row*AST + 64*w + ln*4;
        uint2 pk;
        pk.x = f2bf_pk(acc[rt][0][r], acc[rt][1][r]);
        pk.y = f2bf_pk(acc[rt][2][r], acc[rt][3][r]);
        *(uint2*)pp = pk;
      }
    short8 B2[4];
    loadB<4>(B2, wq + OFF_WA2 + w*2048, lane);
    zeroAcc<2>(acc);
    runGemm<2,2>(acc, B2, aBase, 64*w);
    float b20 = cq[C_BA2 + w*32 + ln];
    float b21 = cq[C_BA2 + w*32 + 16 + ln];
    #pragma unroll
    for (int rt=0;rt<4;rt++)
      #pragma unroll
      for (int r=0;r<4;r++){
        float a0 = acc[rt][0][r] + b20;
        float a1 = acc[rt][1][r] + b21;
        float sm = a0 + a1;
        #pragma unroll
        for (int d=1;d<16;d<<=1) sm += __shfl_xor(sm,d);
        int row = rt*16+q*4+r;
        if (etl[row]==w){
          float vv = vbuf[row];
          float m  = sm*(1.f/32.f);
          float* op = out + (size_t)(rowBlk+row)*32 + ln;
          op[0]  = vv + a0 - m;
          op[16] = vv + a1 - m;
        }
      }
  }
}

// =====================================================================
extern "C" void kernel_launch(void* const* d_in, const int* in_sizes, int n_in,
                              void* d_out, int out_size, void* d_ws, size_t ws_size,
                              hipStream_t stream)
{
  Ptrs p;
  p.state=(const float*)d_in[0];  p.td =(const float*)d_in[1];
  p.W1 =(const float*)d_in[2];  p.b1 =(const float*)d_in[3];  p.g1 =(const float*)d_in[4];  p.be1=(const float*)d_in[5];
  p.W2 =(const float*)d_in[6];  p.b2 =(const float*)d_in[7];  p.g2 =(const float*)d_in[8];  p.be2=(const float*)d_in[9];
  p.W3 =(const float*)d_in[10]; p.b3 =(const float*)d_in[11]; p.g3 =(const float*)d_in[12]; p.be3=(const float*)d_in[13];
  p.Wv1=(const float*)d_in[14]; p.bv1=(const float*)d_in[15]; p.gv =(const float*)d_in[16]; p.bev=(const float*)d_in[17];
  p.Wv2=(const float*)d_in[18]; p.bv2=(const float*)d_in[19];
  p.Wa1=(const float*)d_in[20]; p.ba1=(const float*)d_in[21]; p.ga =(const float*)d_in[22]; p.bea=(const float*)d_in[23];
  p.Wa2=(const float*)d_in[24]; p.ba2=(const float*)d_in[25];
  p.et =(const int*)d_in[26];

  unsigned short* wq = (unsigned short*)d_ws;
  float* cq = (float*)((char*)d_ws + (size_t)NWQ*2);

  const int prepN = NWQ + NCONST;
  hipLaunchKernelGGL(prep_kernel, dim3((prepN+255)/256), dim3(256), 0, stream, p, wq, cq);
  hipLaunchKernelGGL(dqn_main, dim3(NB/TM), dim3(256), 0, stream,
                     p.state, p.td, p.et, (const unsigned short*)wq, (const float*)cq, (float*)d_out);
}